// Round 1
// baseline (2087.668 us; speedup 1.0000x reference)
//
#include <hip/hip_runtime.h>
#include <hip/hip_bf16.h>

// PSHGCN on MI355X. Pipeline:
//  1) M0 = Wp0@W1, M1 = Wp1@W1  (fused: concat is row-wise, so (x@Wp)@W1 = x@(Wp@W1))
//  2) X = relu(x{0,1}@M{0,1} + b1)  (fp32 vector GEMM, LDS-tiled)
//  3) row-normalize X (mean, ddof=1 std, NaN->0 when std==0)
//  4) build CSR for AP (A rows, local P cols) and PA (P rows, local A cols)
//  5) two power passes, each: hA=AP@X, hP=PA@X, then in-place
//     X_A = c0*X_A + cH*hA + cA*(AP@hP),  X_P = c0*X_P + cH*hP + cA*(PA@hA)
//  6) out = X@W2 + b2

#define DD 128

// ---------------- dense: M = Wp @ W1 (two 128x128x128) ----------------
__global__ __launch_bounds__(128) void fuse_w(const float* __restrict__ Wp0,
                                              const float* __restrict__ Wp1,
                                              const float* __restrict__ W1,
                                              float* __restrict__ M0,
                                              float* __restrict__ M1) {
    int m = blockIdx.x >> 7;
    int i = blockIdx.x & 127;
    const float* Wp = m ? Wp1 : Wp0;
    float* M = m ? M1 : M0;
    __shared__ float r[128];
    int t = threadIdx.x;
    r[t] = Wp[i * 128 + t];
    __syncthreads();
    float acc = 0.f;
    #pragma unroll 8
    for (int k = 0; k < 128; ++k) acc += r[k] * W1[k * 128 + t];
    M[i * 128 + t] = acc;
}

// ---------------- dense: X = relu(xin @ M + b1), 32 rows/block ----------------
__global__ __launch_bounds__(256) void gemm_relu(const float* __restrict__ xin,
                                                 const float* __restrict__ M,
                                                 const float* __restrict__ b1,
                                                 float* __restrict__ xout,
                                                 int nrows) {
    __shared__ float Wl[64 * 128];   // 32KB: half of M (k-split)
    __shared__ float xs[32 * 128];   // 16KB: 32 rows of x
    int t = threadIdx.x;
    long row0 = (long)blockIdx.x * 32;
    int rows_this = nrows - (int)row0;
    if (rows_this > 32) rows_this = 32;

    // stage xs (zeros for out-of-range rows)
    #pragma unroll
    for (int it = 0; it < 4; ++it) {
        int g4 = it * 256 + t;        // float4 index, 1024 total
        int g = g4 * 4;
        int rl = g >> 7, c = g & 127;
        float4 val = {0.f, 0.f, 0.f, 0.f};
        if (rl < rows_this) val = *(const float4*)(xin + (row0 + rl) * 128 + c);
        *(float4*)&xs[rl * 128 + c] = val;
    }

    int r0 = (t >> 5) * 4;        // row group 0..28
    int c0 = (t & 31) * 4;        // col group 0..124
    float acc[4][4];
    #pragma unroll
    for (int i = 0; i < 4; ++i)
        #pragma unroll
        for (int j = 0; j < 4; ++j) acc[i][j] = 0.f;

    for (int h = 0; h < 2; ++h) {
        __syncthreads();
        #pragma unroll
        for (int it = 0; it < 8; ++it) {
            int g4 = it * 256 + t;    // 2048 float4 = 8192 floats
            ((float4*)Wl)[g4] = ((const float4*)(M + h * 8192))[g4];
        }
        __syncthreads();
        #pragma unroll 4
        for (int k = 0; k < 64; ++k) {
            float4 w = *(float4*)&Wl[k * 128 + c0];
            int kk = h * 64 + k;
            #pragma unroll
            for (int i = 0; i < 4; ++i) {
                float a = xs[(r0 + i) * 128 + kk];
                acc[i][0] += a * w.x;
                acc[i][1] += a * w.y;
                acc[i][2] += a * w.z;
                acc[i][3] += a * w.w;
            }
        }
    }

    float4 bb = *(const float4*)(b1 + c0);
    #pragma unroll
    for (int i = 0; i < 4; ++i) {
        int row = r0 + i;
        if (row < rows_this) {
            float4 o;
            o.x = acc[i][0] + bb.x; o.x = o.x > 0.f ? o.x : 0.f;
            o.y = acc[i][1] + bb.y; o.y = o.y > 0.f ? o.y : 0.f;
            o.z = acc[i][2] + bb.z; o.z = o.z > 0.f ? o.z : 0.f;
            o.w = acc[i][3] + bb.w; o.w = o.w > 0.f ? o.w : 0.f;
            *(float4*)(xout + (row0 + row) * 128 + c0) = o;
        }
    }
}

// ---------------- row normalize (mean, ddof=1 std, NaN->0) ----------------
__global__ __launch_bounds__(256) void norm_rows(float* __restrict__ X, int n) {
    int row = blockIdx.x * 4 + (threadIdx.x >> 6);
    if (row >= n) return;
    int lane = threadIdx.x & 63;
    float2 v = *(float2*)(X + (long)row * 128 + lane * 2);
    float s = v.x + v.y;
    #pragma unroll
    for (int off = 32; off >= 1; off >>= 1) s += __shfl_xor(s, off);
    float mean = s * (1.0f / 128.0f);
    float dx = v.x - mean, dy = v.y - mean;
    float q = dx * dx + dy * dy;
    #pragma unroll
    for (int off = 32; off >= 1; off >>= 1) q += __shfl_xor(q, off);
    float inv = 0.f;
    if (q > 0.f) inv = 1.0f / sqrtf(q * (1.0f / 127.0f));
    float2 o = {dx * inv, dy * inv};
    *(float2*)(X + (long)row * 128 + lane * 2) = o;
}

// ---------------- CSR build ----------------
__global__ __launch_bounds__(256) void count_rows(const int* __restrict__ rows, int E,
                                                  int rbase, int* __restrict__ cnt) {
    int i = blockIdx.x * 256 + threadIdx.x;
    if (i < E) atomicAdd(&cnt[rows[i] - rbase], 1);
}

__global__ __launch_bounds__(256) void scan1(const int* __restrict__ cnt, int R,
                                             int* __restrict__ rp, int* __restrict__ bt) {
    __shared__ int lds[256];
    int t = threadIdx.x, b = blockIdx.x;
    int base = b * 4096 + t * 16;
    int v[16];
    int s = 0;
    #pragma unroll
    for (int i = 0; i < 16; ++i) {
        int idx = base + i;
        int c = (idx < R) ? cnt[idx] : 0;
        v[i] = s;
        s += c;
    }
    lds[t] = s;
    __syncthreads();
    for (int off = 1; off < 256; off <<= 1) {
        int x = (t >= off) ? lds[t - off] : 0;
        __syncthreads();
        lds[t] += x;
        __syncthreads();
    }
    int excl = lds[t] - s;
    #pragma unroll
    for (int i = 0; i < 16; ++i) {
        int idx = base + i;
        if (idx < R) rp[idx] = excl + v[i];
    }
    if (t == 0) bt[b] = lds[255];
}

__global__ __launch_bounds__(64) void scan2(const int* __restrict__ bt, int B,
                                            int* __restrict__ bo, int* __restrict__ rp,
                                            int R, int E) {
    int t = threadIdx.x;
    int v = (t < B) ? bt[t] : 0;
    int inc = v;
    #pragma unroll
    for (int off = 1; off < 64; off <<= 1) {
        int y = __shfl_up(inc, off);
        if (t >= off) inc += y;
    }
    if (t < B) bo[t] = inc - v;
    if (t == 0) rp[R] = E;
}

__global__ __launch_bounds__(256) void scan3(int* __restrict__ rp, const int* __restrict__ bo,
                                             int* __restrict__ woff, int R) {
    int i = blockIdx.x * 256 + threadIdx.x;
    if (i < R) {
        int val = rp[i] + bo[i >> 12];
        rp[i] = val;
        woff[i] = val;
    }
}

__global__ __launch_bounds__(256) void scatter_edges(const int* __restrict__ rows,
                                                     const int* __restrict__ cols,
                                                     const float* __restrict__ vals,
                                                     int E, int rbase, int cbase,
                                                     int* __restrict__ woff,
                                                     int* __restrict__ sc,
                                                     float* __restrict__ sv) {
    int i = blockIdx.x * 256 + threadIdx.x;
    if (i < E) {
        int r = rows[i] - rbase;
        int p = atomicAdd(&woff[r], 1);
        sc[p] = cols[i] - cbase;
        sv[p] = vals[i];
    }
}

// ---------------- SpMM: wave per row, 2 edges in flight (half-wave each, float4) --------
__global__ __launch_bounds__(256) void spmm_plain(const int* __restrict__ rp,
                                                  const int* __restrict__ sc,
                                                  const float* __restrict__ sv,
                                                  const float* __restrict__ g,
                                                  float* __restrict__ hout, int R) {
    int row = blockIdx.x * 4 + (threadIdx.x >> 6);
    if (row >= R) return;
    int lane = threadIdx.x & 63;
    int half = lane >> 5;
    int f = (lane & 31) << 2;
    int beg = rp[row], end = rp[row + 1];
    float4 acc = {0.f, 0.f, 0.f, 0.f};
    for (int j = beg + half; j < end; j += 2) {
        int c = sc[j];
        float v = sv[j];
        float4 h = *(const float4*)(g + ((long)c << 7) + f);
        acc.x += v * h.x; acc.y += v * h.y; acc.z += v * h.z; acc.w += v * h.w;
    }
    acc.x += __shfl_xor(acc.x, 32);
    acc.y += __shfl_xor(acc.y, 32);
    acc.z += __shfl_xor(acc.z, 32);
    acc.w += __shfl_xor(acc.w, 32);
    if (half == 0) *(float4*)(hout + ((long)row << 7) + f) = acc;
}

// xseg[row] = coe[0]*xseg[row] + coe[ih]*hself[row] + coe[ia]*(rel @ g)[row]
__global__ __launch_bounds__(256) void spmm_update(const int* __restrict__ rp,
                                                   const int* __restrict__ sc,
                                                   const float* __restrict__ sv,
                                                   const float* __restrict__ g,
                                                   const float* __restrict__ hself,
                                                   float* __restrict__ xseg,
                                                   const float* __restrict__ coe,
                                                   int ih, int ia, int R) {
    int row = blockIdx.x * 4 + (threadIdx.x >> 6);
    if (row >= R) return;
    int lane = threadIdx.x & 63;
    int half = lane >> 5;
    int f = (lane & 31) << 2;
    int beg = rp[row], end = rp[row + 1];
    float4 acc = {0.f, 0.f, 0.f, 0.f};
    for (int j = beg + half; j < end; j += 2) {
        int c = sc[j];
        float v = sv[j];
        float4 h = *(const float4*)(g + ((long)c << 7) + f);
        acc.x += v * h.x; acc.y += v * h.y; acc.z += v * h.z; acc.w += v * h.w;
    }
    acc.x += __shfl_xor(acc.x, 32);
    acc.y += __shfl_xor(acc.y, 32);
    acc.z += __shfl_xor(acc.z, 32);
    acc.w += __shfl_xor(acc.w, 32);
    if (half == 0) {
        float c0 = coe[0], ch = coe[ih], ca = coe[ia];
        long o = ((long)row << 7) + f;
        float4 xr = *(float4*)(xseg + o);
        float4 hs = *(const float4*)(hself + o);
        float4 r;
        r.x = c0 * xr.x + ch * hs.x + ca * acc.x;
        r.y = c0 * xr.y + ch * hs.y + ca * acc.y;
        r.z = c0 * xr.z + ch * hs.z + ca * acc.z;
        r.w = c0 * xr.w + ch * hs.w + ca * acc.w;
        *(float4*)(xseg + o) = r;
    }
}

// ---------------- out = X @ W2 + b2  (C=16) ----------------
__global__ __launch_bounds__(256) void out_gemm(const float* __restrict__ X,
                                                const float* __restrict__ W2,
                                                const float* __restrict__ b2,
                                                float* __restrict__ out, int n) {
    __shared__ float w[128 * 16];
    __shared__ float xs[16 * 132];
    __shared__ float bs[16];
    int t = threadIdx.x;
    long row0 = (long)blockIdx.x * 16;
    #pragma unroll
    for (int i = 0; i < 2; ++i) {
        int g4 = i * 256 + t;   // 512 float4 = 2048 floats
        ((float4*)w)[g4] = ((const float4*)W2)[g4];
    }
    if (t < 16) bs[t] = b2[t];
    #pragma unroll
    for (int i = 0; i < 2; ++i) {
        int g4 = i * 256 + t;
        int g = g4 * 4;
        int rl = g >> 7, c = g & 127;
        float4 val = {0.f, 0.f, 0.f, 0.f};
        if (row0 + rl < n) val = *(const float4*)(X + (row0 + rl) * 128 + c);
        *(float4*)&xs[rl * 132 + c] = val;
    }
    __syncthreads();
    int rl = t >> 4, c = t & 15;
    long row = row0 + rl;
    if (row < n) {
        float acc = 0.f;
        #pragma unroll 4
        for (int k = 0; k < 128; ++k) acc += xs[rl * 132 + k] * w[k * 16 + c];
        out[row * 16 + c] = acc + bs[c];
    }
}

extern "C" void kernel_launch(void* const* d_in, const int* in_sizes, int n_in,
                              void* d_out, int out_size, void* d_ws, size_t ws_size,
                              hipStream_t stream) {
    const float* x0  = (const float*)d_in[0];
    const float* x1  = (const float*)d_in[1];
    const float* vap = (const float*)d_in[2];
    const float* vpa = (const float*)d_in[3];
    const int*   rap = (const int*)d_in[4];
    const int*   cap = (const int*)d_in[5];
    const int*   rpa = (const int*)d_in[6];
    const int*   cpa = (const int*)d_in[7];
    const float* Wp0 = (const float*)d_in[8];
    const float* Wp1 = (const float*)d_in[9];
    const float* W1  = (const float*)d_in[10];
    const float* b1  = (const float*)d_in[11];
    const float* W2  = (const float*)d_in[12];
    const float* b2  = (const float*)d_in[13];
    const float* coe = (const float*)d_in[14];
    float* out = (float*)d_out;

    const int NA = in_sizes[0] / 128;
    const int NP = in_sizes[1] / 128;
    const int N  = NA + NP;
    const int E  = in_sizes[2];

    // workspace layout
    char* p = (char*)d_ws;
    auto alloc = [&](size_t bytes) {
        char* r = p;
        p += (bytes + 255) & ~(size_t)255;
        return r;
    };
    float* X   = (float*)alloc((size_t)N * 128 * 4);
    float* hA  = (float*)alloc((size_t)NA * 128 * 4);
    float* hP  = (float*)alloc((size_t)NP * 128 * 4);
    float* M0  = (float*)alloc(128 * 128 * 4);
    float* M1  = (float*)alloc(128 * 128 * 4);
    int* cntA  = (int*)alloc((size_t)NA * 4);
    int* rpA   = (int*)alloc((size_t)(NA + 1) * 4);
    int* wofA  = (int*)alloc((size_t)NA * 4);
    int* btA   = (int*)alloc(64 * 4);
    int* boA   = (int*)alloc(64 * 4);
    int* scA   = (int*)alloc((size_t)E * 4);
    float* svA = (float*)alloc((size_t)E * 4);
    int* cntP  = (int*)alloc((size_t)NP * 4);
    int* rpP   = (int*)alloc((size_t)(NP + 1) * 4);
    int* wofP  = (int*)alloc((size_t)NP * 4);
    int* btP   = (int*)alloc(64 * 4);
    int* boP   = (int*)alloc(64 * 4);
    int* scP   = (int*)alloc((size_t)E * 4);
    float* svP = (float*)alloc((size_t)E * 4);
    if ((size_t)(p - (char*)d_ws) > ws_size) return;  // ws too small: fail loudly

    const int eg = (E + 255) / 256;

    // ---- CSR build (AP: rows A base 0, cols local P = -NA; PA: rows base NA) ----
    hipMemsetAsync(cntA, 0, (size_t)NA * 4, stream);
    hipMemsetAsync(cntP, 0, (size_t)NP * 4, stream);
    count_rows<<<eg, 256, 0, stream>>>(rap, E, 0, cntA);
    count_rows<<<eg, 256, 0, stream>>>(rpa, E, NA, cntP);
    int BA = (NA + 4095) / 4096, BP = (NP + 4095) / 4096;
    scan1<<<BA, 256, 0, stream>>>(cntA, NA, rpA, btA);
    scan1<<<BP, 256, 0, stream>>>(cntP, NP, rpP, btP);
    scan2<<<1, 64, 0, stream>>>(btA, BA, boA, rpA, NA, E);
    scan2<<<1, 64, 0, stream>>>(btP, BP, boP, rpP, NP, E);
    scan3<<<(NA + 255) / 256, 256, 0, stream>>>(rpA, boA, wofA, NA);
    scan3<<<(NP + 255) / 256, 256, 0, stream>>>(rpP, boP, wofP, NP);
    scatter_edges<<<eg, 256, 0, stream>>>(rap, cap, vap, E, 0, NA, wofA, scA, svA);
    scatter_edges<<<eg, 256, 0, stream>>>(rpa, cpa, vpa, E, NA, 0, wofP, scP, svP);

    // ---- dense front-end ----
    fuse_w<<<256, 128, 0, stream>>>(Wp0, Wp1, W1, M0, M1);
    gemm_relu<<<(NA + 31) / 32, 256, 0, stream>>>(x0, M0, b1, X, NA);
    gemm_relu<<<(NP + 31) / 32, 256, 0, stream>>>(x1, M1, b1, X + (size_t)NA * 128, NP);
    norm_rows<<<(N + 3) / 4, 256, 0, stream>>>(X, N);

    const int gA = (NA + 3) / 4, gP = (NP + 3) / 4;
    float* XP = X + (size_t)NA * 128;

    // ---- pass 1 (first_order = AP, PA): A gets coe1/coe3, P gets coe2/coe4 ----
    spmm_plain<<<gA, 256, 0, stream>>>(rpA, scA, svA, XP, hA, NA);
    spmm_plain<<<gP, 256, 0, stream>>>(rpP, scP, svP, X, hP, NP);
    spmm_update<<<gA, 256, 0, stream>>>(rpA, scA, svA, hP, hA, X, coe, 1, 3, NA);
    spmm_update<<<gP, 256, 0, stream>>>(rpP, scP, svP, hA, hP, XP, coe, 2, 4, NP);

    // ---- pass 2 (first_order = PA, AP): P gets coe1/coe3, A gets coe2/coe4 ----
    spmm_plain<<<gA, 256, 0, stream>>>(rpA, scA, svA, XP, hA, NA);
    spmm_plain<<<gP, 256, 0, stream>>>(rpP, scP, svP, X, hP, NP);
    spmm_update<<<gA, 256, 0, stream>>>(rpA, scA, svA, hP, hA, X, coe, 2, 4, NA);
    spmm_update<<<gP, 256, 0, stream>>>(rpP, scP, svP, hA, hP, XP, coe, 1, 3, NP);

    // ---- out = X @ W2 + b2 ----
    out_gemm<<<(N + 15) / 16, 256, 0, stream>>>(X, W2, b2, out, N);
}

// Round 2
// 1540.970 us; speedup vs baseline: 1.3548x; 1.3548x over previous
//
#include <hip/hip_runtime.h>
#include <hip/hip_bf16.h>

// PSHGCN on MI355X — round 2: bf16 gather operands for the 8 SpMMs.
//  X stays fp32 (exact c0*x path + final GEMM); Xbf / hAbf / hPbf are bf16
//  shadows used as gather sources. Quarter-wave per edge (16 lanes x 16B),
//  packed int2 (col, val) edge records.

__device__ inline unsigned short f2bf(float x) {
    unsigned b = __float_as_uint(x);
    unsigned r = (b + 0x7fffu + ((b >> 16) & 1u)) >> 16;
    return (unsigned short)r;
}

// ---------------- dense: M = Wp @ W1 (two 128x128x128) ----------------
__global__ __launch_bounds__(128) void fuse_w(const float* __restrict__ Wp0,
                                              const float* __restrict__ Wp1,
                                              const float* __restrict__ W1,
                                              float* __restrict__ M0,
                                              float* __restrict__ M1) {
    int m = blockIdx.x >> 7;
    int i = blockIdx.x & 127;
    const float* Wp = m ? Wp1 : Wp0;
    float* M = m ? M1 : M0;
    __shared__ float r[128];
    int t = threadIdx.x;
    r[t] = Wp[i * 128 + t];
    __syncthreads();
    float acc = 0.f;
    #pragma unroll 8
    for (int k = 0; k < 128; ++k) acc += r[k] * W1[k * 128 + t];
    M[i * 128 + t] = acc;
}

// ---------------- dense: X = relu(xin @ M + b1), 32 rows/block ----------------
__global__ __launch_bounds__(256) void gemm_relu(const float* __restrict__ xin,
                                                 const float* __restrict__ M,
                                                 const float* __restrict__ b1,
                                                 float* __restrict__ xout,
                                                 int nrows) {
    __shared__ float Wl[64 * 128];
    __shared__ float xs[32 * 128];
    int t = threadIdx.x;
    long row0 = (long)blockIdx.x * 32;
    int rows_this = nrows - (int)row0;
    if (rows_this > 32) rows_this = 32;

    #pragma unroll
    for (int it = 0; it < 4; ++it) {
        int g4 = it * 256 + t;
        int g = g4 * 4;
        int rl = g >> 7, c = g & 127;
        float4 val = {0.f, 0.f, 0.f, 0.f};
        if (rl < rows_this) val = *(const float4*)(xin + (row0 + rl) * 128 + c);
        *(float4*)&xs[rl * 128 + c] = val;
    }

    int r0 = (t >> 5) * 4;
    int c0 = (t & 31) * 4;
    float acc[4][4];
    #pragma unroll
    for (int i = 0; i < 4; ++i)
        #pragma unroll
        for (int j = 0; j < 4; ++j) acc[i][j] = 0.f;

    for (int h = 0; h < 2; ++h) {
        __syncthreads();
        #pragma unroll
        for (int it = 0; it < 8; ++it) {
            int g4 = it * 256 + t;
            ((float4*)Wl)[g4] = ((const float4*)(M + h * 8192))[g4];
        }
        __syncthreads();
        #pragma unroll 4
        for (int k = 0; k < 64; ++k) {
            float4 w = *(float4*)&Wl[k * 128 + c0];
            int kk = h * 64 + k;
            #pragma unroll
            for (int i = 0; i < 4; ++i) {
                float a = xs[(r0 + i) * 128 + kk];
                acc[i][0] += a * w.x;
                acc[i][1] += a * w.y;
                acc[i][2] += a * w.z;
                acc[i][3] += a * w.w;
            }
        }
    }

    float4 bb = *(const float4*)(b1 + c0);
    #pragma unroll
    for (int i = 0; i < 4; ++i) {
        int row = r0 + i;
        if (row < rows_this) {
            float4 o;
            o.x = acc[i][0] + bb.x; o.x = o.x > 0.f ? o.x : 0.f;
            o.y = acc[i][1] + bb.y; o.y = o.y > 0.f ? o.y : 0.f;
            o.z = acc[i][2] + bb.z; o.z = o.z > 0.f ? o.z : 0.f;
            o.w = acc[i][3] + bb.w; o.w = o.w > 0.f ? o.w : 0.f;
            *(float4*)(xout + (row0 + row) * 128 + c0) = o;
        }
    }
}

// ------- row normalize (mean, ddof=1 std, NaN->0); emits fp32 + bf16 -------
__global__ __launch_bounds__(256) void norm_rows(float* __restrict__ X,
                                                 unsigned short* __restrict__ Xbf,
                                                 int n) {
    int row = blockIdx.x * 4 + (threadIdx.x >> 6);
    if (row >= n) return;
    int lane = threadIdx.x & 63;
    float2 v = *(float2*)(X + (long)row * 128 + lane * 2);
    float s = v.x + v.y;
    #pragma unroll
    for (int off = 32; off >= 1; off >>= 1) s += __shfl_xor(s, off);
    float mean = s * (1.0f / 128.0f);
    float dx = v.x - mean, dy = v.y - mean;
    float q = dx * dx + dy * dy;
    #pragma unroll
    for (int off = 32; off >= 1; off >>= 1) q += __shfl_xor(q, off);
    float inv = 0.f;
    if (q > 0.f) inv = 1.0f / sqrtf(q * (1.0f / 127.0f));
    float2 o = {dx * inv, dy * inv};
    *(float2*)(X + (long)row * 128 + lane * 2) = o;
    unsigned pk = (unsigned)f2bf(o.x) | ((unsigned)f2bf(o.y) << 16);
    ((unsigned*)Xbf)[(long)row * 64 + lane] = pk;
}

// ---------------- CSR build ----------------
__global__ __launch_bounds__(256) void count_rows(const int* __restrict__ rows, int E,
                                                  int rbase, int* __restrict__ cnt) {
    int i = blockIdx.x * 256 + threadIdx.x;
    if (i < E) atomicAdd(&cnt[rows[i] - rbase], 1);
}

__global__ __launch_bounds__(256) void scan1(const int* __restrict__ cnt, int R,
                                             int* __restrict__ rp, int* __restrict__ bt) {
    __shared__ int lds[256];
    int t = threadIdx.x, b = blockIdx.x;
    int base = b * 4096 + t * 16;
    int v[16];
    int s = 0;
    #pragma unroll
    for (int i = 0; i < 16; ++i) {
        int idx = base + i;
        int c = (idx < R) ? cnt[idx] : 0;
        v[i] = s;
        s += c;
    }
    lds[t] = s;
    __syncthreads();
    for (int off = 1; off < 256; off <<= 1) {
        int x = (t >= off) ? lds[t - off] : 0;
        __syncthreads();
        lds[t] += x;
        __syncthreads();
    }
    int excl = lds[t] - s;
    #pragma unroll
    for (int i = 0; i < 16; ++i) {
        int idx = base + i;
        if (idx < R) rp[idx] = excl + v[i];
    }
    if (t == 0) bt[b] = lds[255];
}

__global__ __launch_bounds__(64) void scan2(const int* __restrict__ bt, int B,
                                            int* __restrict__ bo, int* __restrict__ rp,
                                            int R, int E) {
    int t = threadIdx.x;
    int v = (t < B) ? bt[t] : 0;
    int inc = v;
    #pragma unroll
    for (int off = 1; off < 64; off <<= 1) {
        int y = __shfl_up(inc, off);
        if (t >= off) inc += y;
    }
    if (t < B) bo[t] = inc - v;
    if (t == 0) rp[R] = E;
}

__global__ __launch_bounds__(256) void scan3(int* __restrict__ rp, const int* __restrict__ bo,
                                             int* __restrict__ woff, int R) {
    int i = blockIdx.x * 256 + threadIdx.x;
    if (i < R) {
        int val = rp[i] + bo[i >> 12];
        rp[i] = val;
        woff[i] = val;
    }
}

__global__ __launch_bounds__(256) void scatter_edges(const int* __restrict__ rows,
                                                     const int* __restrict__ cols,
                                                     const float* __restrict__ vals,
                                                     int E, int rbase, int cbase,
                                                     int* __restrict__ woff,
                                                     int2* __restrict__ scv) {
    int i = blockIdx.x * 256 + threadIdx.x;
    if (i < E) {
        int r = rows[i] - rbase;
        int p = atomicAdd(&woff[r], 1);
        int2 e;
        e.x = cols[i] - cbase;
        e.y = __float_as_int(vals[i]);
        scv[p] = e;
    }
}

// ---- SpMM core: quarter-wave per edge, 16B bf16 gathers, 4 chains/wave ----
// Gather loop shared by plain/update. acc[8] per lane over features f..f+7.
#define SPMM_GATHER_LOOP()                                                    \
    int row = blockIdx.x * 4 + (threadIdx.x >> 6);                            \
    if (row >= R) return;                                                     \
    int lane = threadIdx.x & 63;                                              \
    int q = lane >> 4;                                                        \
    int f = (lane & 15) << 3;                                                 \
    int beg = rp[row], end = rp[row + 1];                                     \
    float acc[8];                                                             \
    _Pragma("unroll")                                                         \
    for (int i = 0; i < 8; ++i) acc[i] = 0.f;                                 \
    for (int j = beg + q; j < end; j += 4) {                                  \
        int2 cv = scv[j];                                                     \
        float v = __int_as_float(cv.y);                                       \
        uint4 h = *(const uint4*)(g + ((long)cv.x << 7) + f);                 \
        acc[0] += v * __uint_as_float(h.x << 16);                             \
        acc[1] += v * __uint_as_float(h.x & 0xffff0000u);                     \
        acc[2] += v * __uint_as_float(h.y << 16);                             \
        acc[3] += v * __uint_as_float(h.y & 0xffff0000u);                     \
        acc[4] += v * __uint_as_float(h.z << 16);                             \
        acc[5] += v * __uint_as_float(h.z & 0xffff0000u);                     \
        acc[6] += v * __uint_as_float(h.w << 16);                             \
        acc[7] += v * __uint_as_float(h.w & 0xffff0000u);                     \
    }                                                                         \
    _Pragma("unroll")                                                         \
    for (int i = 0; i < 8; ++i) {                                             \
        acc[i] += __shfl_xor(acc[i], 16);                                     \
        acc[i] += __shfl_xor(acc[i], 32);                                     \
    }

// h_out(bf16) = rel @ g    (g bf16, row stride 128)
__global__ __launch_bounds__(256) void spmm_plain(const int* __restrict__ rp,
                                                  const int2* __restrict__ scv,
                                                  const unsigned short* __restrict__ g,
                                                  unsigned short* __restrict__ houtbf,
                                                  int R) {
    SPMM_GATHER_LOOP()
    if (q == 0) {
        uint4 o;
        o.x = (unsigned)f2bf(acc[0]) | ((unsigned)f2bf(acc[1]) << 16);
        o.y = (unsigned)f2bf(acc[2]) | ((unsigned)f2bf(acc[3]) << 16);
        o.z = (unsigned)f2bf(acc[4]) | ((unsigned)f2bf(acc[5]) << 16);
        o.w = (unsigned)f2bf(acc[6]) | ((unsigned)f2bf(acc[7]) << 16);
        *(uint4*)(houtbf + ((long)row << 7) + f) = o;
    }
}

// xseg = c0*xseg + ch*hself(bf16) + ca*(rel @ g(bf16));  writes fp32 + bf16
__global__ __launch_bounds__(256) void spmm_update(const int* __restrict__ rp,
                                                   const int2* __restrict__ scv,
                                                   const unsigned short* __restrict__ g,
                                                   const unsigned short* __restrict__ hselfbf,
                                                   float* __restrict__ xseg,
                                                   unsigned short* __restrict__ xsegbf,
                                                   const float* __restrict__ coe,
                                                   int ih, int ia, int R) {
    SPMM_GATHER_LOOP()
    if (q == 0) {
        float c0 = coe[0], ch = coe[ih], ca = coe[ia];
        long o = ((long)row << 7) + f;
        float4 x0 = *(float4*)(xseg + o);
        float4 x1 = *(float4*)(xseg + o + 4);
        uint4 hs = *(const uint4*)(hselfbf + o);
        float r[8];
        r[0] = c0 * x0.x + ch * __uint_as_float(hs.x << 16)        + ca * acc[0];
        r[1] = c0 * x0.y + ch * __uint_as_float(hs.x & 0xffff0000u) + ca * acc[1];
        r[2] = c0 * x0.z + ch * __uint_as_float(hs.y << 16)        + ca * acc[2];
        r[3] = c0 * x0.w + ch * __uint_as_float(hs.y & 0xffff0000u) + ca * acc[3];
        r[4] = c0 * x1.x + ch * __uint_as_float(hs.z << 16)        + ca * acc[4];
        r[5] = c0 * x1.y + ch * __uint_as_float(hs.z & 0xffff0000u) + ca * acc[5];
        r[6] = c0 * x1.z + ch * __uint_as_float(hs.w << 16)        + ca * acc[6];
        r[7] = c0 * x1.w + ch * __uint_as_float(hs.w & 0xffff0000u) + ca * acc[7];
        float4 w0 = {r[0], r[1], r[2], r[3]};
        float4 w1 = {r[4], r[5], r[6], r[7]};
        *(float4*)(xseg + o) = w0;
        *(float4*)(xseg + o + 4) = w1;
        uint4 ob;
        ob.x = (unsigned)f2bf(r[0]) | ((unsigned)f2bf(r[1]) << 16);
        ob.y = (unsigned)f2bf(r[2]) | ((unsigned)f2bf(r[3]) << 16);
        ob.z = (unsigned)f2bf(r[4]) | ((unsigned)f2bf(r[5]) << 16);
        ob.w = (unsigned)f2bf(r[6]) | ((unsigned)f2bf(r[7]) << 16);
        *(uint4*)(xsegbf + o) = ob;
    }
}

// ---------------- out = X @ W2 + b2  (C=16) ----------------
__global__ __launch_bounds__(256) void out_gemm(const float* __restrict__ X,
                                                const float* __restrict__ W2,
                                                const float* __restrict__ b2,
                                                float* __restrict__ out, int n) {
    __shared__ float w[128 * 16];
    __shared__ float xs[16 * 132];
    __shared__ float bs[16];
    int t = threadIdx.x;
    long row0 = (long)blockIdx.x * 16;
    #pragma unroll
    for (int i = 0; i < 2; ++i) {
        int g4 = i * 256 + t;
        ((float4*)w)[g4] = ((const float4*)W2)[g4];
    }
    if (t < 16) bs[t] = b2[t];
    #pragma unroll
    for (int i = 0; i < 2; ++i) {
        int g4 = i * 256 + t;
        int g = g4 * 4;
        int rl = g >> 7, c = g & 127;
        float4 val = {0.f, 0.f, 0.f, 0.f};
        if (row0 + rl < n) val = *(const float4*)(X + (row0 + rl) * 128 + c);
        *(float4*)&xs[rl * 132 + c] = val;
    }
    __syncthreads();
    int rl = t >> 4, c = t & 15;
    long row = row0 + rl;
    if (row < n) {
        float acc = 0.f;
        #pragma unroll 4
        for (int k = 0; k < 128; ++k) acc += xs[rl * 132 + k] * w[k * 16 + c];
        out[row * 16 + c] = acc + bs[c];
    }
}

extern "C" void kernel_launch(void* const* d_in, const int* in_sizes, int n_in,
                              void* d_out, int out_size, void* d_ws, size_t ws_size,
                              hipStream_t stream) {
    const float* x0  = (const float*)d_in[0];
    const float* x1  = (const float*)d_in[1];
    const float* vap = (const float*)d_in[2];
    const float* vpa = (const float*)d_in[3];
    const int*   rap = (const int*)d_in[4];
    const int*   cap = (const int*)d_in[5];
    const int*   rpa = (const int*)d_in[6];
    const int*   cpa = (const int*)d_in[7];
    const float* Wp0 = (const float*)d_in[8];
    const float* Wp1 = (const float*)d_in[9];
    const float* W1  = (const float*)d_in[10];
    const float* b1  = (const float*)d_in[11];
    const float* W2  = (const float*)d_in[12];
    const float* b2  = (const float*)d_in[13];
    const float* coe = (const float*)d_in[14];
    float* out = (float*)d_out;

    const int NA = in_sizes[0] / 128;
    const int NP = in_sizes[1] / 128;
    const int N  = NA + NP;
    const int E  = in_sizes[2];

    char* p = (char*)d_ws;
    auto alloc = [&](size_t bytes) {
        char* r = p;
        p += (bytes + 255) & ~(size_t)255;
        return r;
    };
    float* X            = (float*)alloc((size_t)N * 128 * 4);
    unsigned short* Xbf = (unsigned short*)alloc((size_t)N * 128 * 2);
    unsigned short* hAbf= (unsigned short*)alloc((size_t)NA * 128 * 2);
    unsigned short* hPbf= (unsigned short*)alloc((size_t)NP * 128 * 2);
    float* M0  = (float*)alloc(128 * 128 * 4);
    float* M1  = (float*)alloc(128 * 128 * 4);
    int* cntA  = (int*)alloc((size_t)NA * 4);
    int* rpA   = (int*)alloc((size_t)(NA + 1) * 4);
    int* wofA  = (int*)alloc((size_t)NA * 4);
    int* btA   = (int*)alloc(64 * 4);
    int* boA   = (int*)alloc(64 * 4);
    int2* scvA = (int2*)alloc((size_t)E * 8);
    int* cntP  = (int*)alloc((size_t)NP * 4);
    int* rpP   = (int*)alloc((size_t)(NP + 1) * 4);
    int* wofP  = (int*)alloc((size_t)NP * 4);
    int* btP   = (int*)alloc(64 * 4);
    int* boP   = (int*)alloc(64 * 4);
    int2* scvP = (int2*)alloc((size_t)E * 8);
    if ((size_t)(p - (char*)d_ws) > ws_size) return;

    const int eg = (E + 255) / 256;

    // ---- CSR build ----
    hipMemsetAsync(cntA, 0, (size_t)NA * 4, stream);
    hipMemsetAsync(cntP, 0, (size_t)NP * 4, stream);
    count_rows<<<eg, 256, 0, stream>>>(rap, E, 0, cntA);
    count_rows<<<eg, 256, 0, stream>>>(rpa, E, NA, cntP);
    int BA = (NA + 4095) / 4096, BP = (NP + 4095) / 4096;
    scan1<<<BA, 256, 0, stream>>>(cntA, NA, rpA, btA);
    scan1<<<BP, 256, 0, stream>>>(cntP, NP, rpP, btP);
    scan2<<<1, 64, 0, stream>>>(btA, BA, boA, rpA, NA, E);
    scan2<<<1, 64, 0, stream>>>(btP, BP, boP, rpP, NP, E);
    scan3<<<(NA + 255) / 256, 256, 0, stream>>>(rpA, boA, wofA, NA);
    scan3<<<(NP + 255) / 256, 256, 0, stream>>>(rpP, boP, wofP, NP);
    scatter_edges<<<eg, 256, 0, stream>>>(rap, cap, vap, E, 0, NA, wofA, scvA);
    scatter_edges<<<eg, 256, 0, stream>>>(rpa, cpa, vpa, E, NA, 0, wofP, scvP);

    // ---- dense front-end ----
    fuse_w<<<256, 128, 0, stream>>>(Wp0, Wp1, W1, M0, M1);
    gemm_relu<<<(NA + 31) / 32, 256, 0, stream>>>(x0, M0, b1, X, NA);
    gemm_relu<<<(NP + 31) / 32, 256, 0, stream>>>(x1, M1, b1, X + (size_t)NA * 128, NP);
    norm_rows<<<(N + 3) / 4, 256, 0, stream>>>(X, Xbf, N);

    const int gA = (NA + 3) / 4, gP = (NP + 3) / 4;
    float* XP = X + (size_t)NA * 128;
    unsigned short* XPbf = Xbf + (size_t)NA * 128;

    // ---- pass 1 (AP first): A gets coe1/coe3, P gets coe2/coe4 ----
    spmm_plain<<<gA, 256, 0, stream>>>(rpA, scvA, XPbf, hAbf, NA);
    spmm_plain<<<gP, 256, 0, stream>>>(rpP, scvP, Xbf, hPbf, NP);
    spmm_update<<<gA, 256, 0, stream>>>(rpA, scvA, hPbf, hAbf, X, Xbf, coe, 1, 3, NA);
    spmm_update<<<gP, 256, 0, stream>>>(rpP, scvP, hAbf, hPbf, XP, XPbf, coe, 2, 4, NP);

    // ---- pass 2 (PA first): P gets coe1/coe3, A gets coe2/coe4 ----
    spmm_plain<<<gA, 256, 0, stream>>>(rpA, scvA, XPbf, hAbf, NA);
    spmm_plain<<<gP, 256, 0, stream>>>(rpP, scvP, Xbf, hPbf, NP);
    spmm_update<<<gA, 256, 0, stream>>>(rpA, scvA, hPbf, hAbf, X, Xbf, coe, 2, 4, NA);
    spmm_update<<<gP, 256, 0, stream>>>(rpP, scvP, hAbf, hPbf, XP, XPbf, coe, 1, 3, NP);

    // ---- out = X @ W2 + b2 ----
    out_gemm<<<(N + 15) / 16, 256, 0, stream>>>(X, W2, b2, out, N);
}

// Round 3
// 1454.740 us; speedup vs baseline: 1.4351x; 1.0593x over previous
//
#include <hip/hip_runtime.h>
#include <hip/hip_bf16.h>

// PSHGCN on MI355X — round 3:
//  * two-phase bucketed CSR scatter (L2-local writes, no 8x line amplification)
//  * SpMM gather loop unrolled x2 (8 gathers in flight per wave)
//  X fp32 master + bf16 gather shadows as in round 2.

__device__ inline unsigned short f2bf(float x) {
    unsigned b = __float_as_uint(x);
    unsigned r = (b + 0x7fffu + ((b >> 16) & 1u)) >> 16;
    return (unsigned short)r;
}
__device__ inline float bflo(unsigned u) { return __uint_as_float(u << 16); }
__device__ inline float bfhi(unsigned u) { return __uint_as_float(u & 0xffff0000u); }

// ---------------- dense: M = Wp @ W1 (two 128x128x128) ----------------
__global__ __launch_bounds__(128) void fuse_w(const float* __restrict__ Wp0,
                                              const float* __restrict__ Wp1,
                                              const float* __restrict__ W1,
                                              float* __restrict__ M0,
                                              float* __restrict__ M1) {
    int m = blockIdx.x >> 7;
    int i = blockIdx.x & 127;
    const float* Wp = m ? Wp1 : Wp0;
    float* M = m ? M1 : M0;
    __shared__ float r[128];
    int t = threadIdx.x;
    r[t] = Wp[i * 128 + t];
    __syncthreads();
    float acc = 0.f;
    #pragma unroll 8
    for (int k = 0; k < 128; ++k) acc += r[k] * W1[k * 128 + t];
    M[i * 128 + t] = acc;
}

// ---------------- dense: X = relu(xin @ M + b1), 32 rows/block ----------------
__global__ __launch_bounds__(256) void gemm_relu(const float* __restrict__ xin,
                                                 const float* __restrict__ M,
                                                 const float* __restrict__ b1,
                                                 float* __restrict__ xout,
                                                 int nrows) {
    __shared__ float Wl[64 * 128];
    __shared__ float xs[32 * 128];
    int t = threadIdx.x;
    long row0 = (long)blockIdx.x * 32;
    int rows_this = nrows - (int)row0;
    if (rows_this > 32) rows_this = 32;

    #pragma unroll
    for (int it = 0; it < 4; ++it) {
        int g4 = it * 256 + t;
        int g = g4 * 4;
        int rl = g >> 7, c = g & 127;
        float4 val = {0.f, 0.f, 0.f, 0.f};
        if (rl < rows_this) val = *(const float4*)(xin + (row0 + rl) * 128 + c);
        *(float4*)&xs[rl * 128 + c] = val;
    }

    int r0 = (t >> 5) * 4;
    int c0 = (t & 31) * 4;
    float acc[4][4];
    #pragma unroll
    for (int i = 0; i < 4; ++i)
        #pragma unroll
        for (int j = 0; j < 4; ++j) acc[i][j] = 0.f;

    for (int h = 0; h < 2; ++h) {
        __syncthreads();
        #pragma unroll
        for (int it = 0; it < 8; ++it) {
            int g4 = it * 256 + t;
            ((float4*)Wl)[g4] = ((const float4*)(M + h * 8192))[g4];
        }
        __syncthreads();
        #pragma unroll 4
        for (int k = 0; k < 64; ++k) {
            float4 w = *(float4*)&Wl[k * 128 + c0];
            int kk = h * 64 + k;
            #pragma unroll
            for (int i = 0; i < 4; ++i) {
                float a = xs[(r0 + i) * 128 + kk];
                acc[i][0] += a * w.x;
                acc[i][1] += a * w.y;
                acc[i][2] += a * w.z;
                acc[i][3] += a * w.w;
            }
        }
    }

    float4 bb = *(const float4*)(b1 + c0);
    #pragma unroll
    for (int i = 0; i < 4; ++i) {
        int row = r0 + i;
        if (row < rows_this) {
            float4 o;
            o.x = acc[i][0] + bb.x; o.x = o.x > 0.f ? o.x : 0.f;
            o.y = acc[i][1] + bb.y; o.y = o.y > 0.f ? o.y : 0.f;
            o.z = acc[i][2] + bb.z; o.z = o.z > 0.f ? o.z : 0.f;
            o.w = acc[i][3] + bb.w; o.w = o.w > 0.f ? o.w : 0.f;
            *(float4*)(xout + (row0 + row) * 128 + c0) = o;
        }
    }
}

// ------- row normalize (mean, ddof=1 std, NaN->0); emits fp32 + bf16 -------
__global__ __launch_bounds__(256) void norm_rows(float* __restrict__ X,
                                                 unsigned short* __restrict__ Xbf,
                                                 int n) {
    int row = blockIdx.x * 4 + (threadIdx.x >> 6);
    if (row >= n) return;
    int lane = threadIdx.x & 63;
    float2 v = *(float2*)(X + (long)row * 128 + lane * 2);
    float s = v.x + v.y;
    #pragma unroll
    for (int off = 32; off >= 1; off >>= 1) s += __shfl_xor(s, off);
    float mean = s * (1.0f / 128.0f);
    float dx = v.x - mean, dy = v.y - mean;
    float q = dx * dx + dy * dy;
    #pragma unroll
    for (int off = 32; off >= 1; off >>= 1) q += __shfl_xor(q, off);
    float inv = 0.f;
    if (q > 0.f) inv = 1.0f / sqrtf(q * (1.0f / 127.0f));
    float2 o = {dx * inv, dy * inv};
    *(float2*)(X + (long)row * 128 + lane * 2) = o;
    unsigned pk = (unsigned)f2bf(o.x) | ((unsigned)f2bf(o.y) << 16);
    ((unsigned*)Xbf)[(long)row * 64 + lane] = pk;
}

// ---------------- CSR build: count + scan ----------------
__global__ __launch_bounds__(256) void count_rows(const int* __restrict__ rows, int E,
                                                  int rbase, int* __restrict__ cnt) {
    int i = blockIdx.x * 256 + threadIdx.x;
    if (i < E) atomicAdd(&cnt[rows[i] - rbase], 1);
}

__global__ __launch_bounds__(256) void scan1(const int* __restrict__ cnt, int R,
                                             int* __restrict__ rp, int* __restrict__ bt) {
    __shared__ int lds[256];
    int t = threadIdx.x, b = blockIdx.x;
    int base = b * 4096 + t * 16;
    int v[16];
    int s = 0;
    #pragma unroll
    for (int i = 0; i < 16; ++i) {
        int idx = base + i;
        int c = (idx < R) ? cnt[idx] : 0;
        v[i] = s;
        s += c;
    }
    lds[t] = s;
    __syncthreads();
    for (int off = 1; off < 256; off <<= 1) {
        int x = (t >= off) ? lds[t - off] : 0;
        __syncthreads();
        lds[t] += x;
        __syncthreads();
    }
    int excl = lds[t] - s;
    #pragma unroll
    for (int i = 0; i < 16; ++i) {
        int idx = base + i;
        if (idx < R) rp[idx] = excl + v[i];
    }
    if (t == 0) bt[b] = lds[255];
}

__global__ __launch_bounds__(64) void scan2(const int* __restrict__ bt, int B,
                                            int* __restrict__ bo, int* __restrict__ rp,
                                            int R, int E) {
    int t = threadIdx.x;
    int v = (t < B) ? bt[t] : 0;
    int inc = v;
    #pragma unroll
    for (int off = 1; off < 64; off <<= 1) {
        int y = __shfl_up(inc, off);
        if (t >= off) inc += y;
    }
    if (t < B) bo[t] = inc - v;
    if (t == 0) rp[R] = E;
}

__global__ __launch_bounds__(256) void scan3(int* __restrict__ rp, const int* __restrict__ bo,
                                             int* __restrict__ woff, int R) {
    int i = blockIdx.x * 256 + threadIdx.x;
    if (i < R) {
        int val = rp[i] + bo[i >> 12];
        rp[i] = val;
        woff[i] = val;
    }
}

// bcur[b] = rp[b << sh]  (bucket region start in the edge array)
__global__ __launch_bounds__(256) void binit(const int* __restrict__ rp, int sh, int NR,
                                             int nbuck, int* __restrict__ bcur) {
    int b = blockIdx.x * 256 + threadIdx.x;
    if (b < nbuck) {
        int r = b << sh;
        if (r > NR) r = NR;
        bcur[b] = rp[r];
    }
}

// ---- phase 1: partition edges into row-buckets (L2-local grouped writes) ----
// record: .x = (rowlocal << 18) | col_local   .y = fp32 val bits
__global__ __launch_bounds__(256) void partition_edges(const int* __restrict__ rows,
                                                       const int* __restrict__ cols,
                                                       const float* __restrict__ vals,
                                                       int E, int rbase, int cbase,
                                                       int sh, int nbuck,
                                                       int* __restrict__ bcur,
                                                       int2* __restrict__ tmp) {
    __shared__ int hist[512];
    __shared__ int gbase[512];
    __shared__ int cnt2[512];
    int t = threadIdx.x;
    for (int b = t; b < nbuck; b += 256) { hist[b] = 0; cnt2[b] = 0; }
    __syncthreads();
    long base = (long)blockIdx.x * 4096;
    #pragma unroll
    for (int k = 0; k < 16; ++k) {
        long i = base + k * 256 + t;
        if (i < E) {
            int rl = rows[i] - rbase;
            atomicAdd(&hist[rl >> sh], 1);
        }
    }
    __syncthreads();
    for (int b = t; b < nbuck; b += 256) {
        int h = hist[b];
        gbase[b] = h ? atomicAdd(&bcur[b], h) : 0;
    }
    __syncthreads();
    #pragma unroll
    for (int k = 0; k < 16; ++k) {
        long i = base + k * 256 + t;
        if (i < E) {
            int rl = rows[i] - rbase;
            int b = rl >> sh;
            int rank = atomicAdd(&cnt2[b], 1);
            int2 rec;
            rec.x = ((rl - (b << sh)) << 18) | (cols[i] - cbase);
            rec.y = __float_as_int(vals[i]);
            tmp[gbase[b] + rank] = rec;
        }
    }
}

// ---- phase 2: exact-position scatter within one bucket (block per bucket) ----
__global__ __launch_bounds__(256) void place_edges(const int* __restrict__ rp,
                                                   const int2* __restrict__ tmp,
                                                   int sh, int NR,
                                                   int* __restrict__ woff,
                                                   int2* __restrict__ scv) {
    int b = blockIdx.x;
    int srow = b << sh;
    int erow = srow + (1 << sh);
    if (erow > NR) erow = NR;
    int start = rp[srow], endp = rp[erow];
    for (int i = start + threadIdx.x; i < endp; i += 256) {
        int2 rec = tmp[i];
        int row = srow + (rec.x >> 18);
        int p = atomicAdd(&woff[row], 1);
        int2 o;
        o.x = rec.x & 0x3ffff;
        o.y = rec.y;
        scv[p] = o;
    }
}

// ---- SpMM gather core: quarter-wave per edge, unrolled x2 ----
__device__ inline void spmm_gather(const int* __restrict__ rp,
                                   const int2* __restrict__ scv,
                                   const unsigned short* __restrict__ g,
                                   int row, int q, int f, float* acc) {
    int beg = rp[row], end = rp[row + 1];
    int j = beg + q;
    while (j + 4 < end) {
        int2 c0 = scv[j];
        int2 c1 = scv[j + 4];
        const uint4 h0 = *(const uint4*)(g + ((long)c0.x << 7) + f);
        const uint4 h1 = *(const uint4*)(g + ((long)c1.x << 7) + f);
        float v0 = __int_as_float(c0.y);
        float v1 = __int_as_float(c1.y);
        acc[0] += v0 * bflo(h0.x); acc[1] += v0 * bfhi(h0.x);
        acc[2] += v0 * bflo(h0.y); acc[3] += v0 * bfhi(h0.y);
        acc[4] += v0 * bflo(h0.z); acc[5] += v0 * bfhi(h0.z);
        acc[6] += v0 * bflo(h0.w); acc[7] += v0 * bfhi(h0.w);
        acc[0] += v1 * bflo(h1.x); acc[1] += v1 * bfhi(h1.x);
        acc[2] += v1 * bflo(h1.y); acc[3] += v1 * bfhi(h1.y);
        acc[4] += v1 * bflo(h1.z); acc[5] += v1 * bfhi(h1.z);
        acc[6] += v1 * bflo(h1.w); acc[7] += v1 * bfhi(h1.w);
        j += 8;
    }
    if (j < end) {
        int2 c0 = scv[j];
        const uint4 h0 = *(const uint4*)(g + ((long)c0.x << 7) + f);
        float v0 = __int_as_float(c0.y);
        acc[0] += v0 * bflo(h0.x); acc[1] += v0 * bfhi(h0.x);
        acc[2] += v0 * bflo(h0.y); acc[3] += v0 * bfhi(h0.y);
        acc[4] += v0 * bflo(h0.z); acc[5] += v0 * bfhi(h0.z);
        acc[6] += v0 * bflo(h0.w); acc[7] += v0 * bfhi(h0.w);
    }
    #pragma unroll
    for (int i = 0; i < 8; ++i) {
        acc[i] += __shfl_xor(acc[i], 16);
        acc[i] += __shfl_xor(acc[i], 32);
    }
}

// h_out(bf16) = rel @ g
__global__ __launch_bounds__(256) void spmm_plain(const int* __restrict__ rp,
                                                  const int2* __restrict__ scv,
                                                  const unsigned short* __restrict__ g,
                                                  unsigned short* __restrict__ houtbf,
                                                  int R) {
    int row = blockIdx.x * 4 + (threadIdx.x >> 6);
    if (row >= R) return;
    int lane = threadIdx.x & 63;
    int q = lane >> 4;
    int f = (lane & 15) << 3;
    float acc[8];
    #pragma unroll
    for (int i = 0; i < 8; ++i) acc[i] = 0.f;
    spmm_gather(rp, scv, g, row, q, f, acc);
    if (q == 0) {
        uint4 o;
        o.x = (unsigned)f2bf(acc[0]) | ((unsigned)f2bf(acc[1]) << 16);
        o.y = (unsigned)f2bf(acc[2]) | ((unsigned)f2bf(acc[3]) << 16);
        o.z = (unsigned)f2bf(acc[4]) | ((unsigned)f2bf(acc[5]) << 16);
        o.w = (unsigned)f2bf(acc[6]) | ((unsigned)f2bf(acc[7]) << 16);
        *(uint4*)(houtbf + ((long)row << 7) + f) = o;
    }
}

// xseg = c0*xseg + ch*hself(bf16) + ca*(rel @ g(bf16)); writes fp32 + bf16
__global__ __launch_bounds__(256) void spmm_update(const int* __restrict__ rp,
                                                   const int2* __restrict__ scv,
                                                   const unsigned short* __restrict__ g,
                                                   const unsigned short* __restrict__ hselfbf,
                                                   float* __restrict__ xseg,
                                                   unsigned short* __restrict__ xsegbf,
                                                   const float* __restrict__ coe,
                                                   int ih, int ia, int R) {
    int row = blockIdx.x * 4 + (threadIdx.x >> 6);
    if (row >= R) return;
    int lane = threadIdx.x & 63;
    int q = lane >> 4;
    int f = (lane & 15) << 3;
    float acc[8];
    #pragma unroll
    for (int i = 0; i < 8; ++i) acc[i] = 0.f;
    spmm_gather(rp, scv, g, row, q, f, acc);
    if (q == 0) {
        float c0 = coe[0], ch = coe[ih], ca = coe[ia];
        long o = ((long)row << 7) + f;
        float4 x0 = *(float4*)(xseg + o);
        float4 x1 = *(float4*)(xseg + o + 4);
        uint4 hs = *(const uint4*)(hselfbf + o);
        float r[8];
        r[0] = c0 * x0.x + ch * bflo(hs.x) + ca * acc[0];
        r[1] = c0 * x0.y + ch * bfhi(hs.x) + ca * acc[1];
        r[2] = c0 * x0.z + ch * bflo(hs.y) + ca * acc[2];
        r[3] = c0 * x0.w + ch * bfhi(hs.y) + ca * acc[3];
        r[4] = c0 * x1.x + ch * bflo(hs.z) + ca * acc[4];
        r[5] = c0 * x1.y + ch * bfhi(hs.z) + ca * acc[5];
        r[6] = c0 * x1.z + ch * bflo(hs.w) + ca * acc[6];
        r[7] = c0 * x1.w + ch * bfhi(hs.w) + ca * acc[7];
        float4 w0 = {r[0], r[1], r[2], r[3]};
        float4 w1 = {r[4], r[5], r[6], r[7]};
        *(float4*)(xseg + o) = w0;
        *(float4*)(xseg + o + 4) = w1;
        uint4 ob;
        ob.x = (unsigned)f2bf(r[0]) | ((unsigned)f2bf(r[1]) << 16);
        ob.y = (unsigned)f2bf(r[2]) | ((unsigned)f2bf(r[3]) << 16);
        ob.z = (unsigned)f2bf(r[4]) | ((unsigned)f2bf(r[5]) << 16);
        ob.w = (unsigned)f2bf(r[6]) | ((unsigned)f2bf(r[7]) << 16);
        *(uint4*)(xsegbf + o) = ob;
    }
}

// ---------------- out = X @ W2 + b2  (C=16) ----------------
__global__ __launch_bounds__(256) void out_gemm(const float* __restrict__ X,
                                                const float* __restrict__ W2,
                                                const float* __restrict__ b2,
                                                float* __restrict__ out, int n) {
    __shared__ float w[128 * 16];
    __shared__ float xs[16 * 132];
    __shared__ float bs[16];
    int t = threadIdx.x;
    long row0 = (long)blockIdx.x * 16;
    #pragma unroll
    for (int i = 0; i < 2; ++i) {
        int g4 = i * 256 + t;
        ((float4*)w)[g4] = ((const float4*)W2)[g4];
    }
    if (t < 16) bs[t] = b2[t];
    #pragma unroll
    for (int i = 0; i < 2; ++i) {
        int g4 = i * 256 + t;
        int g = g4 * 4;
        int rl = g >> 7, c = g & 127;
        float4 val = {0.f, 0.f, 0.f, 0.f};
        if (row0 + rl < n) val = *(const float4*)(X + (row0 + rl) * 128 + c);
        *(float4*)&xs[rl * 132 + c] = val;
    }
    __syncthreads();
    int rl = t >> 4, c = t & 15;
    long row = row0 + rl;
    if (row < n) {
        float acc = 0.f;
        #pragma unroll 4
        for (int k = 0; k < 128; ++k) acc += xs[rl * 132 + k] * w[k * 16 + c];
        out[row * 16 + c] = acc + bs[c];
    }
}

extern "C" void kernel_launch(void* const* d_in, const int* in_sizes, int n_in,
                              void* d_out, int out_size, void* d_ws, size_t ws_size,
                              hipStream_t stream) {
    const float* x0  = (const float*)d_in[0];
    const float* x1  = (const float*)d_in[1];
    const float* vap = (const float*)d_in[2];
    const float* vpa = (const float*)d_in[3];
    const int*   rap = (const int*)d_in[4];
    const int*   cap = (const int*)d_in[5];
    const int*   rpa = (const int*)d_in[6];
    const int*   cpa = (const int*)d_in[7];
    const float* Wp0 = (const float*)d_in[8];
    const float* Wp1 = (const float*)d_in[9];
    const float* W1  = (const float*)d_in[10];
    const float* b1  = (const float*)d_in[11];
    const float* W2  = (const float*)d_in[12];
    const float* b2  = (const float*)d_in[13];
    const float* coe = (const float*)d_in[14];
    float* out = (float*)d_out;

    const int NA = in_sizes[0] / 128;
    const int NP = in_sizes[1] / 128;
    const int N  = NA + NP;
    const int E  = in_sizes[2];

    char* p = (char*)d_ws;
    auto alloc = [&](size_t bytes) {
        char* r = p;
        p += (bytes + 255) & ~(size_t)255;
        return r;
    };
    float* X            = (float*)alloc((size_t)N * 128 * 4);
    unsigned short* Xbf = (unsigned short*)alloc((size_t)N * 128 * 2);
    unsigned short* hAbf= (unsigned short*)alloc((size_t)NA * 128 * 2);
    unsigned short* hPbf= (unsigned short*)alloc((size_t)NP * 128 * 2);
    float* M0  = (float*)alloc(128 * 128 * 4);
    float* M1  = (float*)alloc(128 * 128 * 4);
    int* cntA  = (int*)alloc((size_t)NA * 4);
    int* rpA   = (int*)alloc((size_t)(NA + 1) * 4);
    int* wofA  = (int*)alloc((size_t)NA * 4);
    int* btA   = (int*)alloc(64 * 4);
    int* boA   = (int*)alloc(64 * 4);
    int2* scvA = (int2*)alloc((size_t)E * 8);
    int* cntP  = (int*)alloc((size_t)NP * 4);
    int* rpP   = (int*)alloc((size_t)(NP + 1) * 4);
    int* wofP  = (int*)alloc((size_t)NP * 4);
    int* btP   = (int*)alloc(64 * 4);
    int* boP   = (int*)alloc(64 * 4);
    int2* scvP = (int2*)alloc((size_t)E * 8);
    int* bcurA = (int*)alloc(512 * 4);
    int* bcurP = (int*)alloc(512 * 4);
    if ((size_t)(p - (char*)d_ws) > ws_size) return;

    // tmp partition buffers alias X (X is written only after CSR build completes)
    int2* tmpA = (int2*)X;
    int2* tmpP = tmpA + E;

    const int eg = (E + 255) / 256;
    const int SH_A = 8, SH_P = 9;               // 256 / 512 rows per bucket
    const int nbA = (NA + 255) >> 8;            // 391
    const int nbP = (NP + 511) >> 9;            // 293
    const int pg = (E + 4095) / 4096;

    // ---- CSR build ----
    hipMemsetAsync(cntA, 0, (size_t)NA * 4, stream);
    hipMemsetAsync(cntP, 0, (size_t)NP * 4, stream);
    count_rows<<<eg, 256, 0, stream>>>(rap, E, 0, cntA);
    count_rows<<<eg, 256, 0, stream>>>(rpa, E, NA, cntP);
    int BA = (NA + 4095) / 4096, BP = (NP + 4095) / 4096;
    scan1<<<BA, 256, 0, stream>>>(cntA, NA, rpA, btA);
    scan1<<<BP, 256, 0, stream>>>(cntP, NP, rpP, btP);
    scan2<<<1, 64, 0, stream>>>(btA, BA, boA, rpA, NA, E);
    scan2<<<1, 64, 0, stream>>>(btP, BP, boP, rpP, NP, E);
    scan3<<<(NA + 255) / 256, 256, 0, stream>>>(rpA, boA, wofA, NA);
    scan3<<<(NP + 255) / 256, 256, 0, stream>>>(rpP, boP, wofP, NP);
    binit<<<2, 256, 0, stream>>>(rpA, SH_A, NA, nbA, bcurA);
    binit<<<2, 256, 0, stream>>>(rpP, SH_P, NP, nbP, bcurP);
    partition_edges<<<pg, 256, 0, stream>>>(rap, cap, vap, E, 0, NA, SH_A, nbA, bcurA, tmpA);
    partition_edges<<<pg, 256, 0, stream>>>(rpa, cpa, vpa, E, NA, 0, SH_P, nbP, bcurP, tmpP);
    place_edges<<<nbA, 256, 0, stream>>>(rpA, tmpA, SH_A, NA, wofA, scvA);
    place_edges<<<nbP, 256, 0, stream>>>(rpP, tmpP, SH_P, NP, wofP, scvP);

    // ---- dense front-end (X written AFTER tmp aliasing is done with) ----
    fuse_w<<<256, 128, 0, stream>>>(Wp0, Wp1, W1, M0, M1);
    gemm_relu<<<(NA + 31) / 32, 256, 0, stream>>>(x0, M0, b1, X, NA);
    gemm_relu<<<(NP + 31) / 32, 256, 0, stream>>>(x1, M1, b1, X + (size_t)NA * 128, NP);
    norm_rows<<<(N + 3) / 4, 256, 0, stream>>>(X, Xbf, N);

    const int gA = (NA + 3) / 4, gP = (NP + 3) / 4;
    float* XP = X + (size_t)NA * 128;
    unsigned short* XPbf = Xbf + (size_t)NA * 128;

    // ---- pass 1 (AP first): A gets coe1/coe3, P gets coe2/coe4 ----
    spmm_plain<<<gA, 256, 0, stream>>>(rpA, scvA, XPbf, hAbf, NA);
    spmm_plain<<<gP, 256, 0, stream>>>(rpP, scvP, Xbf, hPbf, NP);
    spmm_update<<<gA, 256, 0, stream>>>(rpA, scvA, hPbf, hAbf, X, Xbf, coe, 1, 3, NA);
    spmm_update<<<gP, 256, 0, stream>>>(rpP, scvP, hAbf, hPbf, XP, XPbf, coe, 2, 4, NP);

    // ---- pass 2 (PA first): P gets coe1/coe3, A gets coe2/coe4 ----
    spmm_plain<<<gA, 256, 0, stream>>>(rpA, scvA, XPbf, hAbf, NA);
    spmm_plain<<<gP, 256, 0, stream>>>(rpP, scvP, Xbf, hPbf, NP);
    spmm_update<<<gA, 256, 0, stream>>>(rpA, scvA, hPbf, hAbf, X, Xbf, coe, 2, 4, NA);
    spmm_update<<<gP, 256, 0, stream>>>(rpP, scvP, hAbf, hPbf, XP, XPbf, coe, 1, 3, NP);

    // ---- out = X @ W2 + b2 ----
    out_gemm<<<(N + 15) / 16, 256, 0, stream>>>(X, W2, b2, out, N);
}

// Round 4
// 1379.525 us; speedup vs baseline: 1.5133x; 1.0545x over previous
//
#include <hip/hip_runtime.h>
#include <hip/hip_bf16.h>

// PSHGCN on MI355X — round 4:
//  * unified 2-relation operator M = [[0,AP],[PA,0]] over N rows, global cols
//    -> one CSR build, 4 SpMM dispatches total (2 passes x plain+update)
//  * row-per-quarter SpMM (no cross-lane reduction), unroll x4 => 16 gathers
//    in flight per wave
//  * row-normalization fused into gemm_relu epilogue (norm_rows deleted)
//  X fp32 master + bf16 gather shadows.

__device__ inline unsigned short f2bf(float x) {
    unsigned b = __float_as_uint(x);
    unsigned r = (b + 0x7fffu + ((b >> 16) & 1u)) >> 16;
    return (unsigned short)r;
}
__device__ inline float bflo(unsigned u) { return __uint_as_float(u << 16); }
__device__ inline float bfhi(unsigned u) { return __uint_as_float(u & 0xffff0000u); }

// ---------------- dense: M = Wp @ W1 (two 128x128x128) ----------------
__global__ __launch_bounds__(128) void fuse_w(const float* __restrict__ Wp0,
                                              const float* __restrict__ Wp1,
                                              const float* __restrict__ W1,
                                              float* __restrict__ M0,
                                              float* __restrict__ M1) {
    int m = blockIdx.x >> 7;
    int i = blockIdx.x & 127;
    const float* Wp = m ? Wp1 : Wp0;
    float* M = m ? M1 : M0;
    __shared__ float r[128];
    int t = threadIdx.x;
    r[t] = Wp[i * 128 + t];
    __syncthreads();
    float acc = 0.f;
    #pragma unroll 8
    for (int k = 0; k < 128; ++k) acc += r[k] * W1[k * 128 + t];
    M[i * 128 + t] = acc;
}

// ---- dense: X = normalize(relu(xin @ M + b1)); emits fp32 + bf16 ----
__global__ __launch_bounds__(256) void gemm_relu_norm(const float* __restrict__ xin,
                                                      const float* __restrict__ M,
                                                      const float* __restrict__ b1,
                                                      float* __restrict__ xout,
                                                      unsigned short* __restrict__ xbf,
                                                      int nrows) {
    __shared__ float Wl[64 * 128];
    __shared__ float xs[32 * 128];
    int t = threadIdx.x;
    long row0 = (long)blockIdx.x * 32;
    int rows_this = nrows - (int)row0;
    if (rows_this > 32) rows_this = 32;

    #pragma unroll
    for (int it = 0; it < 4; ++it) {
        int g4 = it * 256 + t;
        int g = g4 * 4;
        int rl = g >> 7, c = g & 127;
        float4 val = {0.f, 0.f, 0.f, 0.f};
        if (rl < rows_this) val = *(const float4*)(xin + (row0 + rl) * 128 + c);
        *(float4*)&xs[rl * 128 + c] = val;
    }

    int r0 = (t >> 5) * 4;
    int c0 = (t & 31) * 4;
    float acc[4][4];
    #pragma unroll
    for (int i = 0; i < 4; ++i)
        #pragma unroll
        for (int j = 0; j < 4; ++j) acc[i][j] = 0.f;

    for (int h = 0; h < 2; ++h) {
        __syncthreads();
        #pragma unroll
        for (int it = 0; it < 8; ++it) {
            int g4 = it * 256 + t;
            ((float4*)Wl)[g4] = ((const float4*)(M + h * 8192))[g4];
        }
        __syncthreads();
        #pragma unroll 4
        for (int k = 0; k < 64; ++k) {
            float4 w = *(float4*)&Wl[k * 128 + c0];
            int kk = h * 64 + k;
            #pragma unroll
            for (int i = 0; i < 4; ++i) {
                float a = xs[(r0 + i) * 128 + kk];
                acc[i][0] += a * w.x;
                acc[i][1] += a * w.y;
                acc[i][2] += a * w.z;
                acc[i][3] += a * w.w;
            }
        }
    }

    float4 bb = *(const float4*)(b1 + c0);
    #pragma unroll
    for (int i = 0; i < 4; ++i) {
        // bias + relu
        float o0 = acc[i][0] + bb.x; o0 = o0 > 0.f ? o0 : 0.f;
        float o1 = acc[i][1] + bb.y; o1 = o1 > 0.f ? o1 : 0.f;
        float o2 = acc[i][2] + bb.z; o2 = o2 > 0.f ? o2 : 0.f;
        float o3 = acc[i][3] + bb.w; o3 = o3 > 0.f ? o3 : 0.f;
        // row stats across the 32 threads holding this row (half-wave)
        float s = o0 + o1 + o2 + o3;
        #pragma unroll
        for (int m = 16; m >= 1; m >>= 1) s += __shfl_xor(s, m);
        float mean = s * (1.0f / 128.0f);
        float d0 = o0 - mean, d1 = o1 - mean, d2 = o2 - mean, d3 = o3 - mean;
        float q = d0 * d0 + d1 * d1 + d2 * d2 + d3 * d3;
        #pragma unroll
        for (int m = 16; m >= 1; m >>= 1) q += __shfl_xor(q, m);
        float inv = 0.f;
        if (q > 0.f) inv = 1.0f / sqrtf(q * (1.0f / 127.0f));
        float z0 = d0 * inv, z1 = d1 * inv, z2 = d2 * inv, z3 = d3 * inv;
        int row = r0 + i;
        if (row < rows_this) {
            float4 o = {z0, z1, z2, z3};
            *(float4*)(xout + (row0 + row) * 128 + c0) = o;
            uint2 pk;
            pk.x = (unsigned)f2bf(z0) | ((unsigned)f2bf(z1) << 16);
            pk.y = (unsigned)f2bf(z2) | ((unsigned)f2bf(z3) << 16);
            *(uint2*)(xbf + (row0 + row) * 128 + c0) = pk;
        }
    }
}

// ---------------- CSR build (unified, N rows, global cols) ----------------
__global__ __launch_bounds__(256) void count_rows(const int* __restrict__ rows, int E,
                                                  int* __restrict__ cnt) {
    int i = blockIdx.x * 256 + threadIdx.x;
    if (i < E) atomicAdd(&cnt[rows[i]], 1);
}

__global__ __launch_bounds__(256) void scan1(const int* __restrict__ cnt, int R,
                                             int* __restrict__ rp, int* __restrict__ bt) {
    __shared__ int lds[256];
    int t = threadIdx.x, b = blockIdx.x;
    int base = b * 4096 + t * 16;
    int v[16];
    int s = 0;
    #pragma unroll
    for (int i = 0; i < 16; ++i) {
        int idx = base + i;
        int c = (idx < R) ? cnt[idx] : 0;
        v[i] = s;
        s += c;
    }
    lds[t] = s;
    __syncthreads();
    for (int off = 1; off < 256; off <<= 1) {
        int x = (t >= off) ? lds[t - off] : 0;
        __syncthreads();
        lds[t] += x;
        __syncthreads();
    }
    int excl = lds[t] - s;
    #pragma unroll
    for (int i = 0; i < 16; ++i) {
        int idx = base + i;
        if (idx < R) rp[idx] = excl + v[i];
    }
    if (t == 0) bt[b] = lds[255];
}

__global__ __launch_bounds__(64) void scan2(const int* __restrict__ bt, int B,
                                            int* __restrict__ bo, int* __restrict__ rp,
                                            int R, int E2) {
    int t = threadIdx.x;
    int v = (t < B) ? bt[t] : 0;
    int inc = v;
    #pragma unroll
    for (int off = 1; off < 64; off <<= 1) {
        int y = __shfl_up(inc, off);
        if (t >= off) inc += y;
    }
    if (t < B) bo[t] = inc - v;
    if (t == 0) rp[R] = E2;
}

__global__ __launch_bounds__(256) void scan3(int* __restrict__ rp, const int* __restrict__ bo,
                                             int* __restrict__ woff, int R) {
    int i = blockIdx.x * 256 + threadIdx.x;
    if (i < R) {
        int val = rp[i] + bo[i >> 12];
        rp[i] = val;
        woff[i] = val;
    }
}

// bcur[b] = rp[b << 9]
__global__ __launch_bounds__(256) void binit(const int* __restrict__ rp, int NR,
                                             int nbuck, int* __restrict__ bcur) {
    int b = blockIdx.x * 256 + threadIdx.x;
    if (b < nbuck) {
        int r = b << 9;
        if (r > NR) r = NR;
        bcur[b] = rp[r];
    }
}

// ---- phase 1: partition edges into 512-row buckets (L2-local writes) ----
// rec.x = (rowlocal << 18) | global_col (N < 2^18), rec.y = fp32 val bits
__global__ __launch_bounds__(256) void partition_edges(const int* __restrict__ rows,
                                                       const int* __restrict__ cols,
                                                       const float* __restrict__ vals,
                                                       int E, int nbuck,
                                                       int* __restrict__ bcur,
                                                       int2* __restrict__ tmp) {
    __shared__ int hist[512];
    __shared__ int gbase[512];
    __shared__ int cnt2[512];
    int t = threadIdx.x;
    for (int b = t; b < nbuck; b += 256) { hist[b] = 0; cnt2[b] = 0; }
    __syncthreads();
    long base = (long)blockIdx.x * 4096;
    #pragma unroll
    for (int k = 0; k < 16; ++k) {
        long i = base + k * 256 + t;
        if (i < E) atomicAdd(&hist[rows[i] >> 9], 1);
    }
    __syncthreads();
    for (int b = t; b < nbuck; b += 256) {
        int h = hist[b];
        gbase[b] = h ? atomicAdd(&bcur[b], h) : 0;
    }
    __syncthreads();
    #pragma unroll
    for (int k = 0; k < 16; ++k) {
        long i = base + k * 256 + t;
        if (i < E) {
            int rl = rows[i];
            int b = rl >> 9;
            int rank = atomicAdd(&cnt2[b], 1);
            int2 rec;
            rec.x = ((rl - (b << 9)) << 18) | cols[i];
            rec.y = __float_as_int(vals[i]);
            tmp[gbase[b] + rank] = rec;
        }
    }
}

// ---- phase 2: exact-position scatter within one bucket ----
__global__ __launch_bounds__(256) void place_edges(const int* __restrict__ rp,
                                                   const int2* __restrict__ tmp,
                                                   int NR,
                                                   int* __restrict__ woff,
                                                   int2* __restrict__ scv) {
    int b = blockIdx.x;
    int srow = b << 9;
    int erow = srow + 512;
    if (erow > NR) erow = NR;
    int start = rp[srow], endp = rp[erow];
    for (int i = start + threadIdx.x; i < endp; i += 256) {
        int2 rec = tmp[i];
        int row = srow + (rec.x >> 18);
        int p = atomicAdd(&woff[row], 1);
        int2 o;
        o.x = rec.x & 0x3ffff;
        o.y = rec.y;
        scv[p] = o;
    }
}

// ---- SpMM core: one row per 16-lane quarter, unroll x4 (16 gathers/wave) ----
__device__ inline void spmm_core(const int* __restrict__ rp,
                                 const int2* __restrict__ scv,
                                 const unsigned short* __restrict__ g,
                                 int row, int f, float* acc) {
    int beg = rp[row], end = rp[row + 1];
    int j = beg;
    for (; j + 4 <= end; j += 4) {
        int2 r0 = scv[j], r1 = scv[j + 1], r2 = scv[j + 2], r3 = scv[j + 3];
        uint4 h0 = *(const uint4*)(g + ((long)r0.x << 7) + f);
        uint4 h1 = *(const uint4*)(g + ((long)r1.x << 7) + f);
        uint4 h2 = *(const uint4*)(g + ((long)r2.x << 7) + f);
        uint4 h3 = *(const uint4*)(g + ((long)r3.x << 7) + f);
        float v0 = __int_as_float(r0.y), v1 = __int_as_float(r1.y);
        float v2 = __int_as_float(r2.y), v3 = __int_as_float(r3.y);
        acc[0] += v0 * bflo(h0.x); acc[1] += v0 * bfhi(h0.x);
        acc[2] += v0 * bflo(h0.y); acc[3] += v0 * bfhi(h0.y);
        acc[4] += v0 * bflo(h0.z); acc[5] += v0 * bfhi(h0.z);
        acc[6] += v0 * bflo(h0.w); acc[7] += v0 * bfhi(h0.w);
        acc[0] += v1 * bflo(h1.x); acc[1] += v1 * bfhi(h1.x);
        acc[2] += v1 * bflo(h1.y); acc[3] += v1 * bfhi(h1.y);
        acc[4] += v1 * bflo(h1.z); acc[5] += v1 * bfhi(h1.z);
        acc[6] += v1 * bflo(h1.w); acc[7] += v1 * bfhi(h1.w);
        acc[0] += v2 * bflo(h2.x); acc[1] += v2 * bfhi(h2.x);
        acc[2] += v2 * bflo(h2.y); acc[3] += v2 * bfhi(h2.y);
        acc[4] += v2 * bflo(h2.z); acc[5] += v2 * bfhi(h2.z);
        acc[6] += v2 * bflo(h2.w); acc[7] += v2 * bfhi(h2.w);
        acc[0] += v3 * bflo(h3.x); acc[1] += v3 * bfhi(h3.x);
        acc[2] += v3 * bflo(h3.y); acc[3] += v3 * bfhi(h3.y);
        acc[4] += v3 * bflo(h3.z); acc[5] += v3 * bfhi(h3.z);
        acc[6] += v3 * bflo(h3.w); acc[7] += v3 * bfhi(h3.w);
    }
    for (; j < end; ++j) {
        int2 r0 = scv[j];
        uint4 h0 = *(const uint4*)(g + ((long)r0.x << 7) + f);
        float v0 = __int_as_float(r0.y);
        acc[0] += v0 * bflo(h0.x); acc[1] += v0 * bfhi(h0.x);
        acc[2] += v0 * bflo(h0.y); acc[3] += v0 * bfhi(h0.y);
        acc[4] += v0 * bflo(h0.z); acc[5] += v0 * bfhi(h0.z);
        acc[6] += v0 * bflo(h0.w); acc[7] += v0 * bfhi(h0.w);
    }
}

// h(bf16) = M @ X(bf16)
__global__ __launch_bounds__(256) void spmm_plain(const int* __restrict__ rp,
                                                  const int2* __restrict__ scv,
                                                  const unsigned short* __restrict__ g,
                                                  unsigned short* __restrict__ houtbf,
                                                  int R) {
    int wave = blockIdx.x * 4 + (threadIdx.x >> 6);
    int lane = threadIdx.x & 63;
    int row = wave * 4 + (lane >> 4);
    if (row >= R) return;
    int f = (lane & 15) << 3;
    float acc[8];
    #pragma unroll
    for (int i = 0; i < 8; ++i) acc[i] = 0.f;
    spmm_core(rp, scv, g, row, f, acc);
    uint4 o;
    o.x = (unsigned)f2bf(acc[0]) | ((unsigned)f2bf(acc[1]) << 16);
    o.y = (unsigned)f2bf(acc[2]) | ((unsigned)f2bf(acc[3]) << 16);
    o.z = (unsigned)f2bf(acc[4]) | ((unsigned)f2bf(acc[5]) << 16);
    o.w = (unsigned)f2bf(acc[6]) | ((unsigned)f2bf(acc[7]) << 16);
    *(uint4*)(houtbf + ((long)row << 7) + f) = o;
}

// X = c0*X + c_h[seg]*h + c_2nd[seg]*(M @ h);  seg = (row<NA) ? A : P
__global__ __launch_bounds__(256) void spmm_update(const int* __restrict__ rp,
                                                   const int2* __restrict__ scv,
                                                   const unsigned short* __restrict__ g,
                                                   float* __restrict__ X,
                                                   unsigned short* __restrict__ Xbf,
                                                   const float* __restrict__ coe,
                                                   int ihA, int iaA, int ihP, int iaP,
                                                   int NA, int R) {
    int wave = blockIdx.x * 4 + (threadIdx.x >> 6);
    int lane = threadIdx.x & 63;
    int row = wave * 4 + (lane >> 4);
    if (row >= R) return;
    int f = (lane & 15) << 3;
    float acc[8];
    #pragma unroll
    for (int i = 0; i < 8; ++i) acc[i] = 0.f;
    spmm_core(rp, scv, g, row, f, acc);

    float c0 = coe[0];
    float ch = coe[row < NA ? ihA : ihP];
    float ca = coe[row < NA ? iaA : iaP];
    long o = ((long)row << 7) + f;
    float4 x0 = *(float4*)(X + o);
    float4 x1 = *(float4*)(X + o + 4);
    uint4 hs = *(const uint4*)(g + o);   // hself = same h buffer, own row
    float r[8];
    r[0] = c0 * x0.x + ch * bflo(hs.x) + ca * acc[0];
    r[1] = c0 * x0.y + ch * bfhi(hs.x) + ca * acc[1];
    r[2] = c0 * x0.z + ch * bflo(hs.y) + ca * acc[2];
    r[3] = c0 * x0.w + ch * bfhi(hs.y) + ca * acc[3];
    r[4] = c0 * x1.x + ch * bflo(hs.z) + ca * acc[4];
    r[5] = c0 * x1.y + ch * bfhi(hs.z) + ca * acc[5];
    r[6] = c0 * x1.z + ch * bflo(hs.w) + ca * acc[6];
    r[7] = c0 * x1.w + ch * bfhi(hs.w) + ca * acc[7];
    float4 w0 = {r[0], r[1], r[2], r[3]};
    float4 w1 = {r[4], r[5], r[6], r[7]};
    *(float4*)(X + o) = w0;
    *(float4*)(X + o + 4) = w1;
    uint4 ob;
    ob.x = (unsigned)f2bf(r[0]) | ((unsigned)f2bf(r[1]) << 16);
    ob.y = (unsigned)f2bf(r[2]) | ((unsigned)f2bf(r[3]) << 16);
    ob.z = (unsigned)f2bf(r[4]) | ((unsigned)f2bf(r[5]) << 16);
    ob.w = (unsigned)f2bf(r[6]) | ((unsigned)f2bf(r[7]) << 16);
    *(uint4*)(Xbf + o) = ob;
}

// ---------------- out = X @ W2 + b2  (C=16) ----------------
__global__ __launch_bounds__(256) void out_gemm(const float* __restrict__ X,
                                                const float* __restrict__ W2,
                                                const float* __restrict__ b2,
                                                float* __restrict__ out, int n) {
    __shared__ float w[128 * 16];
    __shared__ float xs[16 * 132];
    __shared__ float bs[16];
    int t = threadIdx.x;
    long row0 = (long)blockIdx.x * 16;
    #pragma unroll
    for (int i = 0; i < 2; ++i) {
        int g4 = i * 256 + t;
        ((float4*)w)[g4] = ((const float4*)W2)[g4];
    }
    if (t < 16) bs[t] = b2[t];
    #pragma unroll
    for (int i = 0; i < 2; ++i) {
        int g4 = i * 256 + t;
        int g = g4 * 4;
        int rl = g >> 7, c = g & 127;
        float4 val = {0.f, 0.f, 0.f, 0.f};
        if (row0 + rl < n) val = *(const float4*)(X + (row0 + rl) * 128 + c);
        *(float4*)&xs[rl * 132 + c] = val;
    }
    __syncthreads();
    int rl = t >> 4, c = t & 15;
    long row = row0 + rl;
    if (row < n) {
        float acc = 0.f;
        #pragma unroll 4
        for (int k = 0; k < 128; ++k) acc += xs[rl * 132 + k] * w[k * 16 + c];
        out[row * 16 + c] = acc + bs[c];
    }
}

extern "C" void kernel_launch(void* const* d_in, const int* in_sizes, int n_in,
                              void* d_out, int out_size, void* d_ws, size_t ws_size,
                              hipStream_t stream) {
    const float* x0  = (const float*)d_in[0];
    const float* x1  = (const float*)d_in[1];
    const float* vap = (const float*)d_in[2];
    const float* vpa = (const float*)d_in[3];
    const int*   rap = (const int*)d_in[4];
    const int*   cap = (const int*)d_in[5];
    const int*   rpa = (const int*)d_in[6];
    const int*   cpa = (const int*)d_in[7];
    const float* Wp0 = (const float*)d_in[8];
    const float* Wp1 = (const float*)d_in[9];
    const float* W1  = (const float*)d_in[10];
    const float* b1  = (const float*)d_in[11];
    const float* W2  = (const float*)d_in[12];
    const float* b2  = (const float*)d_in[13];
    const float* coe = (const float*)d_in[14];
    float* out = (float*)d_out;

    const int NA = in_sizes[0] / 128;
    const int NP = in_sizes[1] / 128;
    const int N  = NA + NP;
    const int E  = in_sizes[2];
    const int E2 = 2 * E;

    char* p = (char*)d_ws;
    auto alloc = [&](size_t bytes) {
        char* r = p;
        p += (bytes + 255) & ~(size_t)255;
        return r;
    };
    float* X            = (float*)alloc((size_t)N * 128 * 4);
    unsigned short* Xbf = (unsigned short*)alloc((size_t)N * 128 * 2);
    unsigned short* hbf = (unsigned short*)alloc((size_t)N * 128 * 2);
    float* M0  = (float*)alloc(128 * 128 * 4);
    float* M1  = (float*)alloc(128 * 128 * 4);
    int* cnt   = (int*)alloc((size_t)N * 4);
    int* rp    = (int*)alloc((size_t)(N + 1) * 4);
    int* woff  = (int*)alloc((size_t)N * 4);
    int* bt    = (int*)alloc(64 * 4);
    int* bo    = (int*)alloc(64 * 4);
    int2* scv  = (int2*)alloc((size_t)E2 * 8);
    int* bcur  = (int*)alloc(512 * 4);
    if ((size_t)(p - (char*)d_ws) > ws_size) return;

    // tmp partition buffer aliases X (X written only after CSR build)
    int2* tmp = (int2*)X;

    const int eg = (E + 255) / 256;
    const int nbuck = (N + 511) >> 9;            // 489
    const int pg = (E + 4095) / 4096;

    // ---- unified CSR build ----
    hipMemsetAsync(cnt, 0, (size_t)N * 4, stream);
    count_rows<<<eg, 256, 0, stream>>>(rap, E, cnt);
    count_rows<<<eg, 256, 0, stream>>>(rpa, E, cnt);
    int B = (N + 4095) / 4096;                   // 62
    scan1<<<B, 256, 0, stream>>>(cnt, N, rp, bt);
    scan2<<<1, 64, 0, stream>>>(bt, B, bo, rp, N, E2);
    scan3<<<(N + 255) / 256, 256, 0, stream>>>(rp, bo, woff, N);
    binit<<<2, 256, 0, stream>>>(rp, N, nbuck, bcur);
    partition_edges<<<pg, 256, 0, stream>>>(rap, cap, vap, E, nbuck, bcur, tmp);
    partition_edges<<<pg, 256, 0, stream>>>(rpa, cpa, vpa, E, nbuck, bcur, tmp);
    place_edges<<<nbuck, 256, 0, stream>>>(rp, tmp, N, woff, scv);

    // ---- dense front-end (X written AFTER tmp aliasing done) ----
    fuse_w<<<256, 128, 0, stream>>>(Wp0, Wp1, W1, M0, M1);
    gemm_relu_norm<<<(NA + 31) / 32, 256, 0, stream>>>(x0, M0, b1, X, Xbf, NA);
    gemm_relu_norm<<<(NP + 31) / 32, 256, 0, stream>>>(
        x1, M1, b1, X + (size_t)NA * 128, Xbf + (size_t)NA * 128, NP);

    const int sg = (N + 15) / 16;

    // ---- pass 1 (AP first): A rows coe1/coe3, P rows coe2/coe4 ----
    spmm_plain<<<sg, 256, 0, stream>>>(rp, scv, Xbf, hbf, N);
    spmm_update<<<sg, 256, 0, stream>>>(rp, scv, hbf, X, Xbf, coe, 1, 3, 2, 4, NA, N);

    // ---- pass 2 (PA first): P rows coe1/coe3, A rows coe2/coe4 ----
    spmm_plain<<<sg, 256, 0, stream>>>(rp, scv, Xbf, hbf, N);
    spmm_update<<<sg, 256, 0, stream>>>(rp, scv, hbf, X, Xbf, coe, 2, 4, 1, 3, NA, N);

    // ---- out = X @ W2 + b2 ----
    out_gemm<<<(N + 15) / 16, 256, 0, stream>>>(X, W2, b2, out, N);
}

// Round 5
// 1267.112 us; speedup vs baseline: 1.6476x; 1.0887x over previous
//
#include <hip/hip_runtime.h>
#include <hip/hip_bf16.h>

// PSHGCN on MI355X — round 5:
//  * bf16-only node state (fp32 X master eliminated): MLP emits bf16,
//    pass-1 update reads/writes bf16 only
//  * pass-2 update fuses the final out = res2 @ W2 + b2 (res2 fp32 in LDS,
//    never materialized to HBM); out_gemm deleted
//  * unified 2-relation operator, bucketed CSR build, row-per-quarter SpMM
//    unroll x4 as in round 4

__device__ inline unsigned short f2bf(float x) {
    unsigned b = __float_as_uint(x);
    unsigned r = (b + 0x7fffu + ((b >> 16) & 1u)) >> 16;
    return (unsigned short)r;
}
__device__ inline float bflo(unsigned u) { return __uint_as_float(u << 16); }
__device__ inline float bfhi(unsigned u) { return __uint_as_float(u & 0xffff0000u); }

// ---------------- dense: M = Wp @ W1 (two 128x128x128) ----------------
__global__ __launch_bounds__(128) void fuse_w(const float* __restrict__ Wp0,
                                              const float* __restrict__ Wp1,
                                              const float* __restrict__ W1,
                                              float* __restrict__ M0,
                                              float* __restrict__ M1) {
    int m = blockIdx.x >> 7;
    int i = blockIdx.x & 127;
    const float* Wp = m ? Wp1 : Wp0;
    float* M = m ? M1 : M0;
    __shared__ float r[128];
    int t = threadIdx.x;
    r[t] = Wp[i * 128 + t];
    __syncthreads();
    float acc = 0.f;
    #pragma unroll 8
    for (int k = 0; k < 128; ++k) acc += r[k] * W1[k * 128 + t];
    M[i * 128 + t] = acc;
}

// ---- dense: Xbf = normalize(relu(xin @ M + b1))  (bf16 out only) ----
__global__ __launch_bounds__(256) void gemm_relu_norm(const float* __restrict__ xin,
                                                      const float* __restrict__ M,
                                                      const float* __restrict__ b1,
                                                      unsigned short* __restrict__ xbf,
                                                      int nrows) {
    __shared__ float Wl[64 * 128];
    __shared__ float xs[32 * 128];
    int t = threadIdx.x;
    long row0 = (long)blockIdx.x * 32;
    int rows_this = nrows - (int)row0;
    if (rows_this > 32) rows_this = 32;

    #pragma unroll
    for (int it = 0; it < 4; ++it) {
        int g4 = it * 256 + t;
        int g = g4 * 4;
        int rl = g >> 7, c = g & 127;
        float4 val = {0.f, 0.f, 0.f, 0.f};
        if (rl < rows_this) val = *(const float4*)(xin + (row0 + rl) * 128 + c);
        *(float4*)&xs[rl * 128 + c] = val;
    }

    int r0 = (t >> 5) * 4;
    int c0 = (t & 31) * 4;
    float acc[4][4];
    #pragma unroll
    for (int i = 0; i < 4; ++i)
        #pragma unroll
        for (int j = 0; j < 4; ++j) acc[i][j] = 0.f;

    for (int h = 0; h < 2; ++h) {
        __syncthreads();
        #pragma unroll
        for (int it = 0; it < 8; ++it) {
            int g4 = it * 256 + t;
            ((float4*)Wl)[g4] = ((const float4*)(M + h * 8192))[g4];
        }
        __syncthreads();
        #pragma unroll 4
        for (int k = 0; k < 64; ++k) {
            float4 w = *(float4*)&Wl[k * 128 + c0];
            int kk = h * 64 + k;
            #pragma unroll
            for (int i = 0; i < 4; ++i) {
                float a = xs[(r0 + i) * 128 + kk];
                acc[i][0] += a * w.x;
                acc[i][1] += a * w.y;
                acc[i][2] += a * w.z;
                acc[i][3] += a * w.w;
            }
        }
    }

    float4 bb = *(const float4*)(b1 + c0);
    #pragma unroll
    for (int i = 0; i < 4; ++i) {
        float o0 = acc[i][0] + bb.x; o0 = o0 > 0.f ? o0 : 0.f;
        float o1 = acc[i][1] + bb.y; o1 = o1 > 0.f ? o1 : 0.f;
        float o2 = acc[i][2] + bb.z; o2 = o2 > 0.f ? o2 : 0.f;
        float o3 = acc[i][3] + bb.w; o3 = o3 > 0.f ? o3 : 0.f;
        float s = o0 + o1 + o2 + o3;
        #pragma unroll
        for (int m = 16; m >= 1; m >>= 1) s += __shfl_xor(s, m);
        float mean = s * (1.0f / 128.0f);
        float d0 = o0 - mean, d1 = o1 - mean, d2 = o2 - mean, d3 = o3 - mean;
        float q = d0 * d0 + d1 * d1 + d2 * d2 + d3 * d3;
        #pragma unroll
        for (int m = 16; m >= 1; m >>= 1) q += __shfl_xor(q, m);
        float inv = 0.f;
        if (q > 0.f) inv = 1.0f / sqrtf(q * (1.0f / 127.0f));
        int row = r0 + i;
        if (row < rows_this) {
            uint2 pk;
            pk.x = (unsigned)f2bf(d0 * inv) | ((unsigned)f2bf(d1 * inv) << 16);
            pk.y = (unsigned)f2bf(d2 * inv) | ((unsigned)f2bf(d3 * inv) << 16);
            *(uint2*)(xbf + (row0 + row) * 128 + c0) = pk;
        }
    }
}

// ---------------- CSR build (unified, N rows, global cols) ----------------
__global__ __launch_bounds__(256) void count_rows(const int* __restrict__ rows, int E,
                                                  int* __restrict__ cnt) {
    int i = blockIdx.x * 256 + threadIdx.x;
    if (i < E) atomicAdd(&cnt[rows[i]], 1);
}

__global__ __launch_bounds__(256) void scan1(const int* __restrict__ cnt, int R,
                                             int* __restrict__ rp, int* __restrict__ bt) {
    __shared__ int lds[256];
    int t = threadIdx.x, b = blockIdx.x;
    int base = b * 4096 + t * 16;
    int v[16];
    int s = 0;
    #pragma unroll
    for (int i = 0; i < 16; ++i) {
        int idx = base + i;
        int c = (idx < R) ? cnt[idx] : 0;
        v[i] = s;
        s += c;
    }
    lds[t] = s;
    __syncthreads();
    for (int off = 1; off < 256; off <<= 1) {
        int x = (t >= off) ? lds[t - off] : 0;
        __syncthreads();
        lds[t] += x;
        __syncthreads();
    }
    int excl = lds[t] - s;
    #pragma unroll
    for (int i = 0; i < 16; ++i) {
        int idx = base + i;
        if (idx < R) rp[idx] = excl + v[i];
    }
    if (t == 0) bt[b] = lds[255];
}

__global__ __launch_bounds__(64) void scan2(const int* __restrict__ bt, int B,
                                            int* __restrict__ bo, int* __restrict__ rp,
                                            int R, int E2) {
    int t = threadIdx.x;
    int v = (t < B) ? bt[t] : 0;
    int inc = v;
    #pragma unroll
    for (int off = 1; off < 64; off <<= 1) {
        int y = __shfl_up(inc, off);
        if (t >= off) inc += y;
    }
    if (t < B) bo[t] = inc - v;
    if (t == 0) rp[R] = E2;
}

__global__ __launch_bounds__(256) void scan3(int* __restrict__ rp, const int* __restrict__ bo,
                                             int* __restrict__ woff, int R) {
    int i = blockIdx.x * 256 + threadIdx.x;
    if (i < R) {
        int val = rp[i] + bo[i >> 12];
        rp[i] = val;
        woff[i] = val;
    }
}

__global__ __launch_bounds__(256) void binit(const int* __restrict__ rp, int NR,
                                             int nbuck, int* __restrict__ bcur) {
    int b = blockIdx.x * 256 + threadIdx.x;
    if (b < nbuck) {
        int r = b << 9;
        if (r > NR) r = NR;
        bcur[b] = rp[r];
    }
}

// ---- phase 1: partition edges into 512-row buckets (L2-local writes) ----
__global__ __launch_bounds__(256) void partition_edges(const int* __restrict__ rows,
                                                       const int* __restrict__ cols,
                                                       const float* __restrict__ vals,
                                                       int E, int nbuck,
                                                       int* __restrict__ bcur,
                                                       int2* __restrict__ tmp) {
    __shared__ int hist[512];
    __shared__ int gbase[512];
    __shared__ int cnt2[512];
    int t = threadIdx.x;
    for (int b = t; b < nbuck; b += 256) { hist[b] = 0; cnt2[b] = 0; }
    __syncthreads();
    long base = (long)blockIdx.x * 4096;
    #pragma unroll
    for (int k = 0; k < 16; ++k) {
        long i = base + k * 256 + t;
        if (i < E) atomicAdd(&hist[rows[i] >> 9], 1);
    }
    __syncthreads();
    for (int b = t; b < nbuck; b += 256) {
        int h = hist[b];
        gbase[b] = h ? atomicAdd(&bcur[b], h) : 0;
    }
    __syncthreads();
    #pragma unroll
    for (int k = 0; k < 16; ++k) {
        long i = base + k * 256 + t;
        if (i < E) {
            int rl = rows[i];
            int b = rl >> 9;
            int rank = atomicAdd(&cnt2[b], 1);
            int2 rec;
            rec.x = ((rl - (b << 9)) << 18) | cols[i];
            rec.y = __float_as_int(vals[i]);
            tmp[gbase[b] + rank] = rec;
        }
    }
}

// ---- phase 2: exact-position scatter within one bucket ----
__global__ __launch_bounds__(256) void place_edges(const int* __restrict__ rp,
                                                   const int2* __restrict__ tmp,
                                                   int NR,
                                                   int* __restrict__ woff,
                                                   int2* __restrict__ scv) {
    int b = blockIdx.x;
    int srow = b << 9;
    int erow = srow + 512;
    if (erow > NR) erow = NR;
    int start = rp[srow], endp = rp[erow];
    for (int i = start + threadIdx.x; i < endp; i += 256) {
        int2 rec = tmp[i];
        int row = srow + (rec.x >> 18);
        int p = atomicAdd(&woff[row], 1);
        int2 o;
        o.x = rec.x & 0x3ffff;
        o.y = rec.y;
        scv[p] = o;
    }
}

// ---- SpMM core: one row per 16-lane quarter, unroll x4 ----
__device__ inline void spmm_core(const int* __restrict__ rp,
                                 const int2* __restrict__ scv,
                                 const unsigned short* __restrict__ g,
                                 int row, int f, float* acc) {
    int beg = rp[row], end = rp[row + 1];
    int j = beg;
    for (; j + 4 <= end; j += 4) {
        int2 r0 = scv[j], r1 = scv[j + 1], r2 = scv[j + 2], r3 = scv[j + 3];
        uint4 h0 = *(const uint4*)(g + ((long)r0.x << 7) + f);
        uint4 h1 = *(const uint4*)(g + ((long)r1.x << 7) + f);
        uint4 h2 = *(const uint4*)(g + ((long)r2.x << 7) + f);
        uint4 h3 = *(const uint4*)(g + ((long)r3.x << 7) + f);
        float v0 = __int_as_float(r0.y), v1 = __int_as_float(r1.y);
        float v2 = __int_as_float(r2.y), v3 = __int_as_float(r3.y);
        acc[0] += v0 * bflo(h0.x); acc[1] += v0 * bfhi(h0.x);
        acc[2] += v0 * bflo(h0.y); acc[3] += v0 * bfhi(h0.y);
        acc[4] += v0 * bflo(h0.z); acc[5] += v0 * bfhi(h0.z);
        acc[6] += v0 * bflo(h0.w); acc[7] += v0 * bfhi(h0.w);
        acc[0] += v1 * bflo(h1.x); acc[1] += v1 * bfhi(h1.x);
        acc[2] += v1 * bflo(h1.y); acc[3] += v1 * bfhi(h1.y);
        acc[4] += v1 * bflo(h1.z); acc[5] += v1 * bfhi(h1.z);
        acc[6] += v1 * bflo(h1.w); acc[7] += v1 * bfhi(h1.w);
        acc[0] += v2 * bflo(h2.x); acc[1] += v2 * bfhi(h2.x);
        acc[2] += v2 * bflo(h2.y); acc[3] += v2 * bfhi(h2.y);
        acc[4] += v2 * bflo(h2.z); acc[5] += v2 * bfhi(h2.z);
        acc[6] += v2 * bflo(h2.w); acc[7] += v2 * bfhi(h2.w);
        acc[0] += v3 * bflo(h3.x); acc[1] += v3 * bfhi(h3.x);
        acc[2] += v3 * bflo(h3.y); acc[3] += v3 * bfhi(h3.y);
        acc[4] += v3 * bflo(h3.z); acc[5] += v3 * bfhi(h3.z);
        acc[6] += v3 * bflo(h3.w); acc[7] += v3 * bfhi(h3.w);
    }
    for (; j < end; ++j) {
        int2 r0 = scv[j];
        uint4 h0 = *(const uint4*)(g + ((long)r0.x << 7) + f);
        float v0 = __int_as_float(r0.y);
        acc[0] += v0 * bflo(h0.x); acc[1] += v0 * bfhi(h0.x);
        acc[2] += v0 * bflo(h0.y); acc[3] += v0 * bfhi(h0.y);
        acc[4] += v0 * bflo(h0.z); acc[5] += v0 * bfhi(h0.z);
        acc[6] += v0 * bflo(h0.w); acc[7] += v0 * bfhi(h0.w);
    }
}

// h(bf16) = M @ X(bf16)
__global__ __launch_bounds__(256) void spmm_plain(const int* __restrict__ rp,
                                                  const int2* __restrict__ scv,
                                                  const unsigned short* __restrict__ g,
                                                  unsigned short* __restrict__ houtbf,
                                                  int R) {
    int wave = blockIdx.x * 4 + (threadIdx.x >> 6);
    int lane = threadIdx.x & 63;
    int row = wave * 4 + (lane >> 4);
    if (row >= R) return;
    int f = (lane & 15) << 3;
    float acc[8];
    #pragma unroll
    for (int i = 0; i < 8; ++i) acc[i] = 0.f;
    spmm_core(rp, scv, g, row, f, acc);
    uint4 o;
    o.x = (unsigned)f2bf(acc[0]) | ((unsigned)f2bf(acc[1]) << 16);
    o.y = (unsigned)f2bf(acc[2]) | ((unsigned)f2bf(acc[3]) << 16);
    o.z = (unsigned)f2bf(acc[4]) | ((unsigned)f2bf(acc[5]) << 16);
    o.w = (unsigned)f2bf(acc[6]) | ((unsigned)f2bf(acc[7]) << 16);
    *(uint4*)(houtbf + ((long)row << 7) + f) = o;
}

// pass-1 update: Xbf = c0*Xbf + c_h[seg]*h + c_2nd[seg]*(M @ h)   (bf16 in/out)
__global__ __launch_bounds__(256) void spmm_update(const int* __restrict__ rp,
                                                   const int2* __restrict__ scv,
                                                   const unsigned short* __restrict__ g,
                                                   unsigned short* __restrict__ Xbf,
                                                   const float* __restrict__ coe,
                                                   int ihA, int iaA, int ihP, int iaP,
                                                   int NA, int R) {
    int wave = blockIdx.x * 4 + (threadIdx.x >> 6);
    int lane = threadIdx.x & 63;
    int row = wave * 4 + (lane >> 4);
    if (row >= R) return;
    int f = (lane & 15) << 3;
    float acc[8];
    #pragma unroll
    for (int i = 0; i < 8; ++i) acc[i] = 0.f;
    spmm_core(rp, scv, g, row, f, acc);

    float c0 = coe[0];
    float ch = coe[row < NA ? ihA : ihP];
    float ca = coe[row < NA ? iaA : iaP];
    long o = ((long)row << 7) + f;
    uint4 xv = *(const uint4*)(Xbf + o);
    uint4 hs = *(const uint4*)(g + o);
    float r[8];
    r[0] = c0 * bflo(xv.x) + ch * bflo(hs.x) + ca * acc[0];
    r[1] = c0 * bfhi(xv.x) + ch * bfhi(hs.x) + ca * acc[1];
    r[2] = c0 * bflo(xv.y) + ch * bflo(hs.y) + ca * acc[2];
    r[3] = c0 * bfhi(xv.y) + ch * bfhi(hs.y) + ca * acc[3];
    r[4] = c0 * bflo(xv.z) + ch * bflo(hs.z) + ca * acc[4];
    r[5] = c0 * bfhi(xv.z) + ch * bfhi(hs.z) + ca * acc[5];
    r[6] = c0 * bflo(xv.w) + ch * bflo(hs.w) + ca * acc[6];
    r[7] = c0 * bfhi(xv.w) + ch * bfhi(hs.w) + ca * acc[7];
    uint4 ob;
    ob.x = (unsigned)f2bf(r[0]) | ((unsigned)f2bf(r[1]) << 16);
    ob.y = (unsigned)f2bf(r[2]) | ((unsigned)f2bf(r[3]) << 16);
    ob.z = (unsigned)f2bf(r[4]) | ((unsigned)f2bf(r[5]) << 16);
    ob.w = (unsigned)f2bf(r[6]) | ((unsigned)f2bf(r[7]) << 16);
    *(uint4*)(Xbf + o) = ob;
}

// pass-2 update fused with final GEMM:
//   res2(fp32) = c0*Xbf + c_h[seg]*h + c_2nd[seg]*(M @ h)  -> LDS
//   out[row] = res2[row] @ W2 + b2     (res2 never hits HBM)
__global__ __launch_bounds__(256) void spmm_update_out(const int* __restrict__ rp,
                                                       const int2* __restrict__ scv,
                                                       const unsigned short* __restrict__ g,
                                                       const unsigned short* __restrict__ Xbf,
                                                       const float* __restrict__ coe,
                                                       const float* __restrict__ W2,
                                                       const float* __restrict__ b2,
                                                       float* __restrict__ out,
                                                       int ihA, int iaA, int ihP, int iaP,
                                                       int NA, int R) {
    __shared__ float xs[16 * 132];
    __shared__ float w[128 * 16];
    __shared__ float bs[16];
    int t = threadIdx.x;
    #pragma unroll
    for (int i = 0; i < 2; ++i) ((float4*)w)[i * 256 + t] = ((const float4*)W2)[i * 256 + t];
    if (t < 16) bs[t] = b2[t];

    int lane = t & 63;
    int rl = (t >> 6) * 4 + (lane >> 4);
    int row = blockIdx.x * 16 + rl;
    int f = (lane & 15) << 3;
    if (row < R) {
        float acc[8];
        #pragma unroll
        for (int i = 0; i < 8; ++i) acc[i] = 0.f;
        spmm_core(rp, scv, g, row, f, acc);
        float c0 = coe[0];
        float ch = coe[row < NA ? ihA : ihP];
        float ca = coe[row < NA ? iaA : iaP];
        long o = ((long)row << 7) + f;
        uint4 xv = *(const uint4*)(Xbf + o);
        uint4 hs = *(const uint4*)(g + o);
        float* x = &xs[rl * 132 + f];
        x[0] = c0 * bflo(xv.x) + ch * bflo(hs.x) + ca * acc[0];
        x[1] = c0 * bfhi(xv.x) + ch * bfhi(hs.x) + ca * acc[1];
        x[2] = c0 * bflo(xv.y) + ch * bflo(hs.y) + ca * acc[2];
        x[3] = c0 * bfhi(xv.y) + ch * bfhi(hs.y) + ca * acc[3];
        x[4] = c0 * bflo(xv.z) + ch * bflo(hs.z) + ca * acc[4];
        x[5] = c0 * bfhi(xv.z) + ch * bfhi(hs.z) + ca * acc[5];
        x[6] = c0 * bflo(xv.w) + ch * bflo(hs.w) + ca * acc[6];
        x[7] = c0 * bfhi(xv.w) + ch * bfhi(hs.w) + ca * acc[7];
    }
    __syncthreads();
    int orl = t >> 4, c = t & 15;
    long orow = (long)blockIdx.x * 16 + orl;
    if (orow < R) {
        float acc = 0.f;
        #pragma unroll 4
        for (int k = 0; k < 128; ++k) acc += xs[orl * 132 + k] * w[k * 16 + c];
        out[orow * 16 + c] = acc + bs[c];
    }
}

extern "C" void kernel_launch(void* const* d_in, const int* in_sizes, int n_in,
                              void* d_out, int out_size, void* d_ws, size_t ws_size,
                              hipStream_t stream) {
    const float* x0  = (const float*)d_in[0];
    const float* x1  = (const float*)d_in[1];
    const float* vap = (const float*)d_in[2];
    const float* vpa = (const float*)d_in[3];
    const int*   rap = (const int*)d_in[4];
    const int*   cap = (const int*)d_in[5];
    const int*   rpa = (const int*)d_in[6];
    const int*   cpa = (const int*)d_in[7];
    const float* Wp0 = (const float*)d_in[8];
    const float* Wp1 = (const float*)d_in[9];
    const float* W1  = (const float*)d_in[10];
    const float* b1  = (const float*)d_in[11];
    const float* W2  = (const float*)d_in[12];
    const float* b2  = (const float*)d_in[13];
    const float* coe = (const float*)d_in[14];
    float* out = (float*)d_out;

    const int NA = in_sizes[0] / 128;
    const int NP = in_sizes[1] / 128;
    const int N  = NA + NP;
    const int E  = in_sizes[2];
    const int E2 = 2 * E;

    char* p = (char*)d_ws;
    auto alloc = [&](size_t bytes) {
        char* r = p;
        p += (bytes + 255) & ~(size_t)255;
        return r;
    };
    unsigned short* Xbf = (unsigned short*)alloc((size_t)N * 128 * 2);
    unsigned short* hbf = (unsigned short*)alloc((size_t)N * 128 * 2);
    float* M0  = (float*)alloc(128 * 128 * 4);
    float* M1  = (float*)alloc(128 * 128 * 4);
    int* cnt   = (int*)alloc((size_t)N * 4);
    int* rp    = (int*)alloc((size_t)(N + 1) * 4);
    int* woff  = (int*)alloc((size_t)N * 4);
    int* bt    = (int*)alloc(64 * 4);
    int* bo    = (int*)alloc(64 * 4);
    int2* scv  = (int2*)alloc((size_t)E2 * 8);
    int* bcur  = (int*)alloc(512 * 4);
    if ((size_t)(p - (char*)d_ws) > ws_size) return;

    // tmp partition buffer aliases Xbf (Xbf written only after CSR build);
    // E2*8 = 32 MB <= N*256B = 64 MB
    int2* tmp = (int2*)Xbf;

    const int eg = (E + 255) / 256;
    const int nbuck = (N + 511) >> 9;
    const int pg = (E + 4095) / 4096;

    // ---- unified CSR build ----
    hipMemsetAsync(cnt, 0, (size_t)N * 4, stream);
    count_rows<<<eg, 256, 0, stream>>>(rap, E, cnt);
    count_rows<<<eg, 256, 0, stream>>>(rpa, E, cnt);
    int B = (N + 4095) / 4096;
    scan1<<<B, 256, 0, stream>>>(cnt, N, rp, bt);
    scan2<<<1, 64, 0, stream>>>(bt, B, bo, rp, N, E2);
    scan3<<<(N + 255) / 256, 256, 0, stream>>>(rp, bo, woff, N);
    binit<<<2, 256, 0, stream>>>(rp, N, nbuck, bcur);
    partition_edges<<<pg, 256, 0, stream>>>(rap, cap, vap, E, nbuck, bcur, tmp);
    partition_edges<<<pg, 256, 0, stream>>>(rpa, cpa, vpa, E, nbuck, bcur, tmp);
    place_edges<<<nbuck, 256, 0, stream>>>(rp, tmp, N, woff, scv);

    // ---- dense front-end (Xbf written AFTER tmp aliasing done) ----
    fuse_w<<<256, 128, 0, stream>>>(Wp0, Wp1, W1, M0, M1);
    gemm_relu_norm<<<(NA + 31) / 32, 256, 0, stream>>>(x0, M0, b1, Xbf, NA);
    gemm_relu_norm<<<(NP + 31) / 32, 256, 0, stream>>>(
        x1, M1, b1, Xbf + (size_t)NA * 128, NP);

    const int sg = (N + 15) / 16;

    // ---- pass 1 (AP first): A rows coe1/coe3, P rows coe2/coe4 ----
    spmm_plain<<<sg, 256, 0, stream>>>(rp, scv, Xbf, hbf, N);
    spmm_update<<<sg, 256, 0, stream>>>(rp, scv, hbf, Xbf, coe, 1, 3, 2, 4, NA, N);

    // ---- pass 2 (PA first) fused with out = res2 @ W2 + b2 ----
    spmm_plain<<<sg, 256, 0, stream>>>(rp, scv, Xbf, hbf, N);
    spmm_update_out<<<sg, 256, 0, stream>>>(rp, scv, hbf, Xbf, coe,
                                            W2, b2, out, 2, 4, 1, 3, NA, N);
}